// Round 1
// baseline (1922.213 us; speedup 1.0000x reference)
//
#include <hip/hip_runtime.h>

// GAT 2-layer forward on MI355X. N=100000 nodes, E=1.6M edges,
// F_in=256, layer1: H=8 heads x C=8 (D1=64), layer2: H=1 x 16 classes.

#define LRELU(v) ((v) > 0.f ? (v) : 0.2f * (v))

__device__ __forceinline__ unsigned enc_f(float f) {
  unsigned b = __float_as_uint(f);
  return (b & 0x80000000u) ? ~b : (b | 0x80000000u);
}
__device__ __forceinline__ float dec_f(unsigned u) {
  unsigned b = (u & 0x80000000u) ? (u & 0x7FFFFFFFu) : ~u;
  return __uint_as_float(b);
}

__global__ __launch_bounds__(256) void k_zero(float* __restrict__ p, long n) {
  long i = (long)blockIdx.x * 256 + threadIdx.x;
  long stride = (long)gridDim.x * 256;
  for (; i < n; i += stride) p[i] = 0.f;
}

// h1[N,64] = x[N,256] @ W1[256,64]
__global__ __launch_bounds__(256) void k_gemm1(const float* __restrict__ x,
                                               const float* __restrict__ W,
                                               float* __restrict__ h1, int N) {
  __shared__ float sX[32][256];  // 32 KB
  const int t = threadIdx.x;
  const int n0 = blockIdx.x * 32;
  for (int i = t; i < 32 * 256; i += 256) {
    int r = i >> 8, c = i & 255;
    int n = n0 + r;
    sX[r][c] = (n < N) ? x[(long)n * 256 + c] : 0.f;
  }
  __syncthreads();
  const int col = t & 63;
  const int rg = t >> 6;  // 0..3, each handles 8 rows
  float acc[8];
#pragma unroll
  for (int i = 0; i < 8; ++i) acc[i] = 0.f;
  for (int kk = 0; kk < 256; kk += 4) {
    float w0 = W[(kk + 0) * 64 + col];
    float w1 = W[(kk + 1) * 64 + col];
    float w2 = W[(kk + 2) * 64 + col];
    float w3 = W[(kk + 3) * 64 + col];
#pragma unroll
    for (int rr = 0; rr < 8; ++rr) {
      const float4 xv = *(const float4*)&sX[rg * 8 + rr][kk];
      acc[rr] += xv.x * w0 + xv.y * w1 + xv.z * w2 + xv.w * w3;
    }
  }
#pragma unroll
  for (int rr = 0; rr < 8; ++rr) {
    int n = n0 + rg * 8 + rr;
    if (n < N) h1[(long)n * 64 + col] = acc[rr];
  }
}

// a_s[n,h] = sum_c h1[n,h,c]*attS[h,c]; a_d likewise. one thread per (n,h)
__global__ __launch_bounds__(256) void k_attn1(const float* __restrict__ h1,
                                               const float* __restrict__ attS,
                                               const float* __restrict__ attD,
                                               float* __restrict__ a_s,
                                               float* __restrict__ a_d, int N) {
  int i = blockIdx.x * 256 + threadIdx.x;  // i = n*8 + h
  if (i >= N * 8) return;
  int h = i & 7;
  const float4* hp = (const float4*)&h1[(long)i * 8];
  float4 v0 = hp[0], v1 = hp[1];
  const float4* s0 = (const float4*)&attS[h * 8];
  const float4* d0 = (const float4*)&attD[h * 8];
  float4 sa = s0[0], sb = s0[1], da = d0[0], db = d0[1];
  a_s[i] = v0.x * sa.x + v0.y * sa.y + v0.z * sa.z + v0.w * sa.w +
           v1.x * sb.x + v1.y * sb.y + v1.z * sb.z + v1.w * sb.w;
  a_d[i] = v0.x * da.x + v0.y * da.y + v0.z * da.z + v0.w * da.w +
           v1.x * db.x + v1.y * db.y + v1.z * db.z + v1.w * db.w;
}

__global__ __launch_bounds__(256) void k_edge_max1(const int* __restrict__ ei,
                                                   const float* __restrict__ a_s,
                                                   const float* __restrict__ a_d,
                                                   unsigned* __restrict__ mx, int E) {
  int e = blockIdx.x * 256 + threadIdx.x;
  if (e >= E) return;
  int s = ei[e], d = ei[E + e];
#pragma unroll
  for (int h = 0; h < 8; ++h) {
    float v = a_s[s * 8 + h] + a_d[d * 8 + h];
    v = LRELU(v);
    atomicMax(&mx[d * 8 + h], enc_f(v));
  }
}

__global__ __launch_bounds__(256) void k_edge_sum1(const int* __restrict__ ei,
                                                   const float* __restrict__ a_s,
                                                   const float* __restrict__ a_d,
                                                   const unsigned* __restrict__ mx,
                                                   float* __restrict__ ssum, int E) {
  int e = blockIdx.x * 256 + threadIdx.x;
  if (e >= E) return;
  int s = ei[e], d = ei[E + e];
#pragma unroll
  for (int h = 0; h < 8; ++h) {
    float v = a_s[s * 8 + h] + a_d[d * 8 + h];
    v = LRELU(v);
    atomicAdd(&ssum[d * 8 + h], __expf(v - dec_f(mx[d * 8 + h])));
  }
}

// one thread per (edge, col), col in [0,64). wave = 1 edge -> coalesced
__global__ __launch_bounds__(256) void k_agg1(const int* __restrict__ ei,
                                              const float* __restrict__ a_s,
                                              const float* __restrict__ a_d,
                                              const unsigned* __restrict__ mx,
                                              const float* __restrict__ ssum,
                                              const float* __restrict__ h1,
                                              float* __restrict__ agg, int E) {
  long idx = (long)blockIdx.x * 256 + threadIdx.x;
  int e = (int)(idx >> 6);
  if (e >= E) return;
  int col = (int)(idx & 63);
  int h = col >> 3;
  int s = ei[e], d = ei[E + e];
  float v = a_s[s * 8 + h] + a_d[d * 8 + h];
  v = LRELU(v);
  float alpha = __expf(v - dec_f(mx[d * 8 + h])) / (ssum[d * 8 + h] + 1e-16f);
  atomicAdd(&agg[(long)d * 64 + col], h1[(long)s * 64 + col] * alpha);
}

// h1b = elu(agg + b1)
__global__ __launch_bounds__(256) void k_elu(const float* __restrict__ agg,
                                             const float* __restrict__ b1,
                                             float* __restrict__ h1b, long n) {
  long i = (long)blockIdx.x * 256 + threadIdx.x;
  if (i >= n) return;
  float v = agg[i] + b1[i & 63];
  h1b[i] = v > 0.f ? v : (__expf(v) - 1.f);
}

// h2[N,16] = h1b[N,64] @ W2[64,16]
__global__ __launch_bounds__(256) void k_gemm2(const float* __restrict__ h1b,
                                               const float* __restrict__ W2,
                                               float* __restrict__ h2, int N) {
  __shared__ float sW[64][16];
  __shared__ float sX[16][64];
  const int t = threadIdx.x;
  const int n0 = blockIdx.x * 16;
  for (int i = t; i < 64 * 16; i += 256) sW[i >> 4][i & 15] = W2[i];
  for (int i = t; i < 16 * 64; i += 256) {
    int r = i >> 6, c = i & 63;
    int n = n0 + r;
    sX[r][c] = (n < N) ? h1b[(long)n * 64 + c] : 0.f;
  }
  __syncthreads();
  int c = t & 15, r = t >> 4;
  float acc = 0.f;
#pragma unroll
  for (int k = 0; k < 64; ++k) acc += sX[r][k] * sW[k][c];
  int n = n0 + r;
  if (n < N) h2[(long)n * 16 + c] = acc;
}

__global__ __launch_bounds__(256) void k_attn2(const float* __restrict__ h2,
                                               const float* __restrict__ attS,
                                               const float* __restrict__ attD,
                                               float* __restrict__ a_s,
                                               float* __restrict__ a_d, int N) {
  int n = blockIdx.x * 256 + threadIdx.x;
  if (n >= N) return;
  const float4* hp = (const float4*)&h2[(long)n * 16];
  float ss = 0.f, dd = 0.f;
#pragma unroll
  for (int q = 0; q < 4; ++q) {
    float4 v = hp[q];
    float4 sv = ((const float4*)attS)[q];
    float4 dv = ((const float4*)attD)[q];
    ss += v.x * sv.x + v.y * sv.y + v.z * sv.z + v.w * sv.w;
    dd += v.x * dv.x + v.y * dv.y + v.z * dv.z + v.w * dv.w;
  }
  a_s[n] = ss;
  a_d[n] = dd;
}

__global__ __launch_bounds__(256) void k_edge_max2(const int* __restrict__ ei,
                                                   const float* __restrict__ a_s,
                                                   const float* __restrict__ a_d,
                                                   unsigned* __restrict__ mx, int E) {
  int e = blockIdx.x * 256 + threadIdx.x;
  if (e >= E) return;
  float v = a_s[ei[e]] + a_d[ei[E + e]];
  v = LRELU(v);
  atomicMax(&mx[ei[E + e]], enc_f(v));
}

__global__ __launch_bounds__(256) void k_edge_sum2(const int* __restrict__ ei,
                                                   const float* __restrict__ a_s,
                                                   const float* __restrict__ a_d,
                                                   const unsigned* __restrict__ mx,
                                                   float* __restrict__ ssum, int E) {
  int e = blockIdx.x * 256 + threadIdx.x;
  if (e >= E) return;
  int d = ei[E + e];
  float v = a_s[ei[e]] + a_d[d];
  v = LRELU(v);
  atomicAdd(&ssum[d], __expf(v - dec_f(mx[d])));
}

// one thread per (edge, c), c in [0,16)
__global__ __launch_bounds__(256) void k_agg2(const int* __restrict__ ei,
                                              const float* __restrict__ a_s,
                                              const float* __restrict__ a_d,
                                              const unsigned* __restrict__ mx,
                                              const float* __restrict__ ssum,
                                              const float* __restrict__ h2,
                                              float* __restrict__ out, int E) {
  long idx = (long)blockIdx.x * 256 + threadIdx.x;
  int e = (int)(idx >> 4);
  if (e >= E) return;
  int c = (int)(idx & 15);
  int s = ei[e], d = ei[E + e];
  float v = a_s[s] + a_d[d];
  v = LRELU(v);
  float alpha = __expf(v - dec_f(mx[d])) / (ssum[d] + 1e-16f);
  atomicAdd(&out[(long)d * 16 + c], h2[(long)s * 16 + c] * alpha);
}

__global__ __launch_bounds__(256) void k_lsm(float* __restrict__ out,
                                             const float* __restrict__ b2, int N) {
  int n = blockIdx.x * 256 + threadIdx.x;
  if (n >= N) return;
  float v[16];
  float m = -1e30f;
#pragma unroll
  for (int c = 0; c < 16; ++c) {
    v[c] = out[(long)n * 16 + c] + b2[c];
    m = fmaxf(m, v[c]);
  }
  float sum = 0.f;
#pragma unroll
  for (int c = 0; c < 16; ++c) sum += __expf(v[c] - m);
  float lse = m + __logf(sum);
#pragma unroll
  for (int c = 0; c < 16; ++c) out[(long)n * 16 + c] = v[c] - lse;
}

extern "C" void kernel_launch(void* const* d_in, const int* in_sizes, int n_in,
                              void* d_out, int out_size, void* d_ws, size_t ws_size,
                              hipStream_t stream) {
  const float* x = (const float*)d_in[0];
  const int* ei = (const int*)d_in[1];
  const float* W1 = (const float*)d_in[2];
  const float* attS1 = (const float*)d_in[3];
  const float* attD1 = (const float*)d_in[4];
  const float* b1 = (const float*)d_in[5];
  const float* W2 = (const float*)d_in[6];
  const float* attS2 = (const float*)d_in[7];
  const float* attD2 = (const float*)d_in[8];
  const float* b2 = (const float*)d_in[9];
  float* out = (float*)d_out;

  const int N = in_sizes[0] / 256;  // 100000
  const int E = in_sizes[1] / 2;    // 1600000

  // ws layout (floats): [h1:64N][agg1:64N][as1:8N][ad1:8N][max1:8N][s1:8N] = 160N
  float* ws = (float*)d_ws;
  float* h1 = ws;                          // later holds h1b (elu out)
  float* agg1 = ws + (long)64 * N;         // later holds h2
  float* as1 = ws + (long)128 * N;         // layer2: as2 at +0, ad2 at +N, max2 +2N, s2 +3N
  float* ad1 = ws + (long)136 * N;
  unsigned* max1 = (unsigned*)(ws + (long)144 * N);
  float* s1 = ws + (long)152 * N;

  float* as2 = as1;
  float* ad2 = as1 + N;
  unsigned* max2 = (unsigned*)(as1 + 2 * (long)N);
  float* s2 = as1 + 3 * (long)N;

  const int ZG = 2048;

  // ---- layer 1 ----
  k_zero<<<ZG, 256, 0, stream>>>(agg1, (long)96 * N);  // agg1+as1+ad1+max1+s1
  k_gemm1<<<(N + 31) / 32, 256, 0, stream>>>(x, W1, h1, N);
  k_attn1<<<(N * 8 + 255) / 256, 256, 0, stream>>>(h1, attS1, attD1, as1, ad1, N);
  k_edge_max1<<<(E + 255) / 256, 256, 0, stream>>>(ei, as1, ad1, max1, E);
  k_edge_sum1<<<(E + 255) / 256, 256, 0, stream>>>(ei, as1, ad1, max1, s1, E);
  k_agg1<<<(int)(((long)E * 64 + 255) / 256), 256, 0, stream>>>(ei, as1, ad1, max1, s1,
                                                                h1, agg1, E);
  k_elu<<<(int)(((long)64 * N + 255) / 256), 256, 0, stream>>>(agg1, b1, h1, (long)64 * N);

  // ---- layer 2 ----
  k_gemm2<<<(N + 15) / 16, 256, 0, stream>>>(h1, W2, agg1 /*h2*/, N);
  k_attn2<<<(N + 255) / 256, 256, 0, stream>>>(agg1, attS2, attD2, as2, ad2, N);
  k_zero<<<ZG, 256, 0, stream>>>(as1 + 2 * (long)N, (long)2 * N);  // max2, s2
  k_zero<<<ZG, 256, 0, stream>>>(out, (long)16 * N);
  k_edge_max2<<<(E + 255) / 256, 256, 0, stream>>>(ei, as2, ad2, max2, E);
  k_edge_sum2<<<(E + 255) / 256, 256, 0, stream>>>(ei, as2, ad2, max2, s2, E);
  k_agg2<<<(int)(((long)E * 16 + 255) / 256), 256, 0, stream>>>(ei, as2, ad2, max2, s2,
                                                                agg1, out, E);
  k_lsm<<<(N + 255) / 256, 256, 0, stream>>>(out, b2, N);
}

// Round 2
// 810.205 us; speedup vs baseline: 2.3725x; 2.3725x over previous
//
#include <hip/hip_runtime.h>

// GAT 2-layer forward, CSR-based (no f32 scatter atomics).
// N=100000, E=1.6M, F_in=256, L1: 8 heads x 8 = 64, L2: 1 head x 16.

#define LRELU(v) ((v) > 0.f ? (v) : 0.2f * (v))
#define NEG_BIG -3.4e38f

__global__ __launch_bounds__(256) void k_zero_i(int* __restrict__ p, int n) {
  int i = blockIdx.x * 256 + threadIdx.x;
  int stride = gridDim.x * 256;
  for (; i < n; i += stride) p[i] = 0;
}

__global__ __launch_bounds__(256) void k_deg(const int* __restrict__ ei, int* __restrict__ deg,
                                             int E) {
  int e = blockIdx.x * 256 + threadIdx.x;
  if (e >= E) return;
  atomicAdd(&deg[ei[E + e]], 1);
}

// single-workgroup exclusive scan of deg[N] -> off[N+1], also copies to cursor
__global__ __launch_bounds__(1024) void k_scan(const int* __restrict__ deg,
                                               int* __restrict__ off,
                                               int* __restrict__ cursor, int N) {
  __shared__ int part[1024];
  const int t = threadIdx.x;
  const int C = (N + 1023) / 1024;
  const int lo = t * C, hi = min(lo + C, N);
  int s = 0;
  for (int i = lo; i < hi; ++i) s += deg[i];
  part[t] = s;
  __syncthreads();
  for (int ofs = 1; ofs < 1024; ofs <<= 1) {
    int v = (t >= ofs) ? part[t - ofs] : 0;
    __syncthreads();
    part[t] += v;
    __syncthreads();
  }
  int run = (t > 0) ? part[t - 1] : 0;
  for (int i = lo; i < hi; ++i) {
    int dv = deg[i];
    off[i] = run;
    cursor[i] = run;
    run += dv;
  }
  if (t == 1023) off[N] = part[1023];
}

__global__ __launch_bounds__(256) void k_scatter(const int* __restrict__ ei,
                                                 int* __restrict__ cursor,
                                                 int* __restrict__ csr, int E) {
  int e = blockIdx.x * 256 + threadIdx.x;
  if (e >= E) return;
  int d = ei[E + e];
  int p = atomicAdd(&cursor[d], 1);
  csr[p] = ei[e];
}

// h1[N,64] = x[N,256] @ W1[256,64]
__global__ __launch_bounds__(256) void k_gemm1(const float* __restrict__ x,
                                               const float* __restrict__ W,
                                               float* __restrict__ h1, int N) {
  __shared__ float sX[32][256];
  const int t = threadIdx.x;
  const int n0 = blockIdx.x * 32;
  for (int i = t; i < 32 * 256; i += 256) {
    int r = i >> 8, c = i & 255;
    int n = n0 + r;
    sX[r][c] = (n < N) ? x[(long)n * 256 + c] : 0.f;
  }
  __syncthreads();
  const int col = t & 63;
  const int rg = t >> 6;
  float acc[8];
#pragma unroll
  for (int i = 0; i < 8; ++i) acc[i] = 0.f;
  for (int kk = 0; kk < 256; kk += 4) {
    float w0 = W[(kk + 0) * 64 + col];
    float w1 = W[(kk + 1) * 64 + col];
    float w2 = W[(kk + 2) * 64 + col];
    float w3 = W[(kk + 3) * 64 + col];
#pragma unroll
    for (int rr = 0; rr < 8; ++rr) {
      const float4 xv = *(const float4*)&sX[rg * 8 + rr][kk];
      acc[rr] += xv.x * w0 + xv.y * w1 + xv.z * w2 + xv.w * w3;
    }
  }
#pragma unroll
  for (int rr = 0; rr < 8; ++rr) {
    int n = n0 + rg * 8 + rr;
    if (n < N) h1[(long)n * 64 + col] = acc[rr];
  }
}

__global__ __launch_bounds__(256) void k_attn1(const float* __restrict__ h1,
                                               const float* __restrict__ attS,
                                               const float* __restrict__ attD,
                                               float* __restrict__ a_s,
                                               float* __restrict__ a_d, int N) {
  int i = blockIdx.x * 256 + threadIdx.x;  // i = n*8 + h
  if (i >= N * 8) return;
  int h = i & 7;
  const float4* hp = (const float4*)&h1[(long)i * 8];
  float4 v0 = hp[0], v1 = hp[1];
  const float4* s0 = (const float4*)&attS[h * 8];
  const float4* d0 = (const float4*)&attD[h * 8];
  float4 sa = s0[0], sb = s0[1], da = d0[0], db = d0[1];
  a_s[i] = v0.x * sa.x + v0.y * sa.y + v0.z * sa.z + v0.w * sa.w +
           v1.x * sb.x + v1.y * sb.y + v1.z * sb.z + v1.w * sb.w;
  a_d[i] = v0.x * da.x + v0.y * da.y + v0.z * da.z + v0.w * da.w +
           v1.x * db.x + v1.y * db.y + v1.z * db.z + v1.w * db.w;
}

// one wave per dst node: segment softmax (8 heads) + aggregate 64 cols + bias + ELU
__global__ __launch_bounds__(256) void k_fused1(const int* __restrict__ csr,
                                                const int* __restrict__ off,
                                                const float* __restrict__ as_,
                                                const float* __restrict__ ad_,
                                                const float* __restrict__ h1,
                                                const float* __restrict__ b1,
                                                float* __restrict__ h1b, int N) {
  int wave = (blockIdx.x * 256 + threadIdx.x) >> 6;
  if (wave >= N) return;
  const int lane = threadIdx.x & 63;
  const int d = wave;
  const int r0 = off[d];
  const int deg = off[d + 1] - r0;

  if (deg == 0) {
    float v = b1[lane];
    h1b[(long)d * 64 + lane] = v > 0.f ? v : __expf(v) - 1.f;
    return;
  }

  const float4* dp = (const float4*)&ad_[(long)d * 8];
  float4 da = dp[0], db = dp[1];

  // pass 1: per-lane max over its edges; keep first chunk's e in regs
  float em[8], e0[8];
#pragma unroll
  for (int h = 0; h < 8; ++h) em[h] = NEG_BIG;
  for (int j0 = 0; j0 < deg; j0 += 64) {
    int j = j0 + lane;
    float e[8];
    if (j < deg) {
      int s = csr[r0 + j];
      const float4* ap = (const float4*)&as_[(long)s * 8];
      float4 a = ap[0], b = ap[1];
      e[0] = LRELU(a.x + da.x); e[1] = LRELU(a.y + da.y);
      e[2] = LRELU(a.z + da.z); e[3] = LRELU(a.w + da.w);
      e[4] = LRELU(b.x + db.x); e[5] = LRELU(b.y + db.y);
      e[6] = LRELU(b.z + db.z); e[7] = LRELU(b.w + db.w);
    } else {
#pragma unroll
      for (int h = 0; h < 8; ++h) e[h] = NEG_BIG;
    }
    if (j0 == 0) {
#pragma unroll
      for (int h = 0; h < 8; ++h) e0[h] = e[h];
    }
#pragma unroll
    for (int h = 0; h < 8; ++h) em[h] = fmaxf(em[h], e[h]);
  }
  // cross-lane max
#pragma unroll
  for (int h = 0; h < 8; ++h) {
#pragma unroll
    for (int ofs = 32; ofs >= 1; ofs >>= 1) em[h] = fmaxf(em[h], __shfl_xor(em[h], ofs));
  }

  // pass 2: sum of exp
  float sm[8];
#pragma unroll
  for (int h = 0; h < 8; ++h) sm[h] = __expf(e0[h] - em[h]);  // invalid lanes -> exp(-big)=0
  for (int j0 = 64; j0 < deg; j0 += 64) {
    int j = j0 + lane;
    if (j < deg) {
      int s = csr[r0 + j];
      const float4* ap = (const float4*)&as_[(long)s * 8];
      float4 a = ap[0], b = ap[1];
      float e[8];
      e[0] = LRELU(a.x + da.x); e[1] = LRELU(a.y + da.y);
      e[2] = LRELU(a.z + da.z); e[3] = LRELU(a.w + da.w);
      e[4] = LRELU(b.x + db.x); e[5] = LRELU(b.y + db.y);
      e[6] = LRELU(b.z + db.z); e[7] = LRELU(b.w + db.w);
#pragma unroll
      for (int h = 0; h < 8; ++h) sm[h] += __expf(e[h] - em[h]);
    }
  }
#pragma unroll
  for (int h = 0; h < 8; ++h) {
#pragma unroll
    for (int ofs = 32; ofs >= 1; ofs >>= 1) sm[h] += __shfl_xor(sm[h], ofs);
  }

  // pass 3: lanes = 64 output cols
  const int h = lane >> 3;
  float Mh = em[0], Sh = sm[0];
#pragma unroll
  for (int q = 1; q < 8; ++q) {
    if (h == q) { Mh = em[q]; Sh = sm[q]; }
  }
  const float adh = ((const float*)&da)[0];  // replaced below by proper pick
  float adv;
  {
    float tmp[8] = {da.x, da.y, da.z, da.w, db.x, db.y, db.z, db.w};
    adv = tmp[0];
#pragma unroll
    for (int q = 1; q < 8; ++q)
      if (h == q) adv = tmp[q];
  }
  (void)adh;
  const float inv = 1.f / (Sh + 1e-16f);
  float acc = 0.f;
  for (int j = 0; j < deg; ++j) {
    int s = csr[r0 + j];
    float e = LRELU(as_[(long)s * 8 + h] + adv);
    float alpha = __expf(e - Mh) * inv;
    acc += alpha * h1[(long)s * 64 + lane];
  }
  float v = acc + b1[lane];
  h1b[(long)d * 64 + lane] = v > 0.f ? v : __expf(v) - 1.f;
}

// h2[N,16] = h1b[N,64] @ W2[64,16]
__global__ __launch_bounds__(256) void k_gemm2(const float* __restrict__ h1b,
                                               const float* __restrict__ W2,
                                               float* __restrict__ h2, int N) {
  __shared__ float sW[64][16];
  __shared__ float sX[16][64];
  const int t = threadIdx.x;
  const int n0 = blockIdx.x * 16;
  for (int i = t; i < 64 * 16; i += 256) sW[i >> 4][i & 15] = W2[i];
  for (int i = t; i < 16 * 64; i += 256) {
    int r = i >> 6, c = i & 63;
    int n = n0 + r;
    sX[r][c] = (n < N) ? h1b[(long)n * 64 + c] : 0.f;
  }
  __syncthreads();
  int c = t & 15, r = t >> 4;
  float acc = 0.f;
#pragma unroll
  for (int k = 0; k < 64; ++k) acc += sX[r][k] * sW[k][c];
  int n = n0 + r;
  if (n < N) h2[(long)n * 16 + c] = acc;
}

__global__ __launch_bounds__(256) void k_attn2(const float* __restrict__ h2,
                                               const float* __restrict__ attS,
                                               const float* __restrict__ attD,
                                               float* __restrict__ a_s,
                                               float* __restrict__ a_d, int N) {
  int n = blockIdx.x * 256 + threadIdx.x;
  if (n >= N) return;
  const float4* hp = (const float4*)&h2[(long)n * 16];
  float ss = 0.f, dd = 0.f;
#pragma unroll
  for (int q = 0; q < 4; ++q) {
    float4 v = hp[q];
    float4 sv = ((const float4*)attS)[q];
    float4 dv = ((const float4*)attD)[q];
    ss += v.x * sv.x + v.y * sv.y + v.z * sv.z + v.w * sv.w;
    dd += v.x * dv.x + v.y * dv.y + v.z * dv.z + v.w * dv.w;
  }
  a_s[n] = ss;
  a_d[n] = dd;
}

// one wave per dst: softmax + aggregate 16 cols (quarter-waves) + bias + log_softmax
__global__ __launch_bounds__(256) void k_fused2(const int* __restrict__ csr,
                                                const int* __restrict__ off,
                                                const float* __restrict__ as_,
                                                const float* __restrict__ ad_,
                                                const float* __restrict__ h2,
                                                const float* __restrict__ b2,
                                                float* __restrict__ out, int N) {
  int wave = (blockIdx.x * 256 + threadIdx.x) >> 6;
  if (wave >= N) return;
  const int lane = threadIdx.x & 63;
  const int d = wave;
  const int r0 = off[d];
  const int deg = off[d + 1] - r0;
  const float add = ad_[d];

  float em = NEG_BIG, e0 = NEG_BIG;
  for (int j0 = 0; j0 < deg; j0 += 64) {
    int j = j0 + lane;
    float e = NEG_BIG;
    if (j < deg) e = LRELU(as_[csr[r0 + j]] + add);
    if (j0 == 0) e0 = e;
    em = fmaxf(em, e);
  }
#pragma unroll
  for (int ofs = 32; ofs >= 1; ofs >>= 1) em = fmaxf(em, __shfl_xor(em, ofs));

  float sm = (deg > 0) ? __expf(e0 - em) : 0.f;
  for (int j0 = 64; j0 < deg; j0 += 64) {
    int j = j0 + lane;
    if (j < deg) sm += __expf(LRELU(as_[csr[r0 + j]] + add) - em);
  }
#pragma unroll
  for (int ofs = 32; ofs >= 1; ofs >>= 1) sm += __shfl_xor(sm, ofs);
  const float inv = 1.f / (sm + 1e-16f);

  const int sub = lane >> 4, col = lane & 15;
  float acc = 0.f;
  for (int j = sub; j < deg; j += 4) {
    int s = csr[r0 + j];
    float e = LRELU(as_[s] + add);
    float alpha = __expf(e - em) * inv;
    acc += alpha * h2[(long)s * 16 + col];
  }
  acc += __shfl_xor(acc, 16);
  acc += __shfl_xor(acc, 32);

  float v = acc + b2[col];
  float mm = v;
#pragma unroll
  for (int ofs = 1; ofs < 16; ofs <<= 1) mm = fmaxf(mm, __shfl_xor(mm, ofs));
  float ex = __expf(v - mm), ssum = ex;
#pragma unroll
  for (int ofs = 1; ofs < 16; ofs <<= 1) ssum += __shfl_xor(ssum, ofs);
  if (sub == 0) out[(long)d * 16 + col] = v - (mm + __logf(ssum));
}

extern "C" void kernel_launch(void* const* d_in, const int* in_sizes, int n_in,
                              void* d_out, int out_size, void* d_ws, size_t ws_size,
                              hipStream_t stream) {
  const float* x = (const float*)d_in[0];
  const int* ei = (const int*)d_in[1];
  const float* W1 = (const float*)d_in[2];
  const float* attS1 = (const float*)d_in[3];
  const float* attD1 = (const float*)d_in[4];
  const float* b1 = (const float*)d_in[5];
  const float* W2 = (const float*)d_in[6];
  const float* attS2 = (const float*)d_in[7];
  const float* attD2 = (const float*)d_in[8];
  const float* b2 = (const float*)d_in[9];
  float* out = (float*)d_out;

  const int N = in_sizes[0] / 256;
  const int E = in_sizes[1] / 2;

  // ws layout (float offsets):
  // [0,64N): h1; after k_fused1 dead -> h2[16N) at 0, as2 at 16N, ad2 at 17N
  // [64N,128N): h1b
  // [128N,144N): csr (int)
  // [144N,145N+1): off (int)
  // [146N,147N): deg (int)
  // [147N,148N): cursor (int)
  float* ws = (float*)d_ws;
  float* h1 = ws;
  float* h1b = ws + (long)64 * N;
  int* csr = (int*)(ws + (long)128 * N);
  int* off = (int*)(ws + (long)144 * N);
  int* deg = (int*)(ws + (long)146 * N);
  int* cursor = (int*)(ws + (long)147 * N);

  float* h2 = ws;
  float* as2 = ws + (long)16 * N;
  float* ad2 = ws + (long)17 * N;

  // a_s1/a_d1 live in d_out (dead before the final write)
  float* as1 = out;
  float* ad1 = out + (long)8 * N;

  const int EB = (E + 255) / 256;

  // CSR build
  k_zero_i<<<512, 256, 0, stream>>>(deg, N);
  k_deg<<<EB, 256, 0, stream>>>(ei, deg, E);
  k_scan<<<1, 1024, 0, stream>>>(deg, off, cursor, N);
  k_scatter<<<EB, 256, 0, stream>>>(ei, cursor, csr, E);

  // layer 1
  k_gemm1<<<(N + 31) / 32, 256, 0, stream>>>(x, W1, h1, N);
  k_attn1<<<(N * 8 + 255) / 256, 256, 0, stream>>>(h1, attS1, attD1, as1, ad1, N);
  k_fused1<<<(N + 3) / 4, 256, 0, stream>>>(csr, off, as1, ad1, h1, b1, h1b, N);

  // layer 2
  k_gemm2<<<(N + 15) / 16, 256, 0, stream>>>(h1b, W2, h2, N);
  k_attn2<<<(N + 255) / 256, 256, 0, stream>>>(h2, attS2, attD2, as2, ad2, N);
  k_fused2<<<(N + 3) / 4, 256, 0, stream>>>(csr, off, as2, ad2, h2, b2, out, N);
}

// Round 3
// 597.265 us; speedup vs baseline: 3.2184x; 1.3565x over previous
//
#include <hip/hip_runtime.h>

// GAT 2-layer forward, CSR-based (no f32 scatter atomics), parallel scan.
// N=100000, E=1.6M, F_in=256, L1: 8 heads x 8 = 64, L2: 1 head x 16.

#define LRELU(v) ((v) > 0.f ? (v) : 0.2f * (v))
#define NEG_BIG -3.4e38f
#define SCAN_CHUNK 1024  // elements per block in hierarchical scan

__global__ __launch_bounds__(256) void k_zero_i(int* __restrict__ p, int n) {
  int i = blockIdx.x * 256 + threadIdx.x;
  int stride = gridDim.x * 256;
  for (; i < n; i += stride) p[i] = 0;
}

__global__ __launch_bounds__(256) void k_deg(const int* __restrict__ ei, int* __restrict__ deg,
                                             int E) {
  int e = blockIdx.x * 256 + threadIdx.x;
  if (e >= E) return;
  atomicAdd(&deg[ei[E + e]], 1);
}

// phase A: per-block sums of SCAN_CHUNK elements
__global__ __launch_bounds__(256) void k_scan_part(const int* __restrict__ deg,
                                                   int* __restrict__ part, int N) {
  __shared__ int sm[256];
  const int t = threadIdx.x;
  const int base = blockIdx.x * SCAN_CHUNK + t * 4;
  int s = 0;
#pragma unroll
  for (int q = 0; q < 4; ++q) {
    int i = base + q;
    if (i < N) s += deg[i];
  }
  sm[t] = s;
  __syncthreads();
  for (int ofs = 128; ofs >= 1; ofs >>= 1) {
    if (t < ofs) sm[t] += sm[t + ofs];
    __syncthreads();
  }
  if (t == 0) part[blockIdx.x] = sm[0];
}

// phase B: single small block exclusive-scans part[nb] in place
__global__ __launch_bounds__(256) void k_scan_top(int* __restrict__ part, int nb) {
  __shared__ int sm[256];
  const int t = threadIdx.x;
  sm[t] = (t < nb) ? part[t] : 0;
  __syncthreads();
  for (int ofs = 1; ofs < 256; ofs <<= 1) {
    int v = (t >= ofs) ? sm[t - ofs] : 0;
    __syncthreads();
    sm[t] += v;
    __syncthreads();
  }
  if (t < nb) part[t] = (t > 0) ? sm[t - 1] : 0;  // exclusive
}

// phase C: in-chunk exclusive prefix + chunk base -> off, cursor
__global__ __launch_bounds__(256) void k_scan_final(const int* __restrict__ deg,
                                                    const int* __restrict__ part,
                                                    int* __restrict__ off,
                                                    int* __restrict__ cursor, int N, int E) {
  __shared__ int sm[256];
  const int t = threadIdx.x;
  const int base = blockIdx.x * SCAN_CHUNK + t * 4;
  int d[4];
  int s = 0;
#pragma unroll
  for (int q = 0; q < 4; ++q) {
    int i = base + q;
    d[q] = (i < N) ? deg[i] : 0;
    s += d[q];
  }
  sm[t] = s;
  __syncthreads();
  for (int ofs = 1; ofs < 256; ofs <<= 1) {
    int v = (t >= ofs) ? sm[t - ofs] : 0;
    __syncthreads();
    sm[t] += v;
    __syncthreads();
  }
  int run = part[blockIdx.x] + ((t > 0) ? sm[t - 1] : 0);
#pragma unroll
  for (int q = 0; q < 4; ++q) {
    int i = base + q;
    if (i < N) {
      off[i] = run;
      cursor[i] = run;
      run += d[q];
    }
  }
  if (blockIdx.x == 0 && t == 0) off[N] = E;
}

__global__ __launch_bounds__(256) void k_scatter(const int* __restrict__ ei,
                                                 int* __restrict__ cursor,
                                                 int* __restrict__ csr, int E) {
  int e = blockIdx.x * 256 + threadIdx.x;
  if (e >= E) return;
  int d = ei[E + e];
  int p = atomicAdd(&cursor[d], 1);
  csr[p] = ei[e];
}

// h1[N,64] = x[N,256] @ W1[256,64]
__global__ __launch_bounds__(256) void k_gemm1(const float* __restrict__ x,
                                               const float* __restrict__ W,
                                               float* __restrict__ h1, int N) {
  __shared__ float sX[32][256];
  const int t = threadIdx.x;
  const int n0 = blockIdx.x * 32;
  for (int i = t; i < 32 * 256; i += 256) {
    int r = i >> 8, c = i & 255;
    int n = n0 + r;
    sX[r][c] = (n < N) ? x[(long)n * 256 + c] : 0.f;
  }
  __syncthreads();
  const int col = t & 63;
  const int rg = t >> 6;
  float acc[8];
#pragma unroll
  for (int i = 0; i < 8; ++i) acc[i] = 0.f;
  for (int kk = 0; kk < 256; kk += 4) {
    float w0 = W[(kk + 0) * 64 + col];
    float w1 = W[(kk + 1) * 64 + col];
    float w2 = W[(kk + 2) * 64 + col];
    float w3 = W[(kk + 3) * 64 + col];
#pragma unroll
    for (int rr = 0; rr < 8; ++rr) {
      const float4 xv = *(const float4*)&sX[rg * 8 + rr][kk];
      acc[rr] += xv.x * w0 + xv.y * w1 + xv.z * w2 + xv.w * w3;
    }
  }
#pragma unroll
  for (int rr = 0; rr < 8; ++rr) {
    int n = n0 + rg * 8 + rr;
    if (n < N) h1[(long)n * 64 + col] = acc[rr];
  }
}

__global__ __launch_bounds__(256) void k_attn1(const float* __restrict__ h1,
                                               const float* __restrict__ attS,
                                               const float* __restrict__ attD,
                                               float* __restrict__ a_s,
                                               float* __restrict__ a_d, int N) {
  int i = blockIdx.x * 256 + threadIdx.x;  // i = n*8 + h
  if (i >= N * 8) return;
  int h = i & 7;
  const float4* hp = (const float4*)&h1[(long)i * 8];
  float4 v0 = hp[0], v1 = hp[1];
  const float4* s0 = (const float4*)&attS[h * 8];
  const float4* d0 = (const float4*)&attD[h * 8];
  float4 sa = s0[0], sb = s0[1], da = d0[0], db = d0[1];
  a_s[i] = v0.x * sa.x + v0.y * sa.y + v0.z * sa.z + v0.w * sa.w +
           v1.x * sb.x + v1.y * sb.y + v1.z * sb.z + v1.w * sb.w;
  a_d[i] = v0.x * da.x + v0.y * da.y + v0.z * da.z + v0.w * da.w +
           v1.x * db.x + v1.y * db.y + v1.z * db.z + v1.w * db.w;
}

// one wave per dst node: segment softmax (8 heads) + aggregate 64 cols + bias + ELU
__global__ __launch_bounds__(256) void k_fused1(const int* __restrict__ csr,
                                                const int* __restrict__ off,
                                                const float* __restrict__ as_,
                                                const float* __restrict__ ad_,
                                                const float* __restrict__ h1,
                                                const float* __restrict__ b1,
                                                float* __restrict__ h1b, int N) {
  int wave = (blockIdx.x * 256 + threadIdx.x) >> 6;
  if (wave >= N) return;
  const int lane = threadIdx.x & 63;
  const int d = wave;
  const int r0 = off[d];
  const int deg = off[d + 1] - r0;

  if (deg == 0) {
    float v = b1[lane];
    h1b[(long)d * 64 + lane] = v > 0.f ? v : __expf(v) - 1.f;
    return;
  }

  const float4* dp = (const float4*)&ad_[(long)d * 8];
  float4 da = dp[0], db = dp[1];

  // pass 1: per-lane max over its edges; keep first chunk's e in regs
  float em[8], e0[8];
#pragma unroll
  for (int h = 0; h < 8; ++h) em[h] = NEG_BIG;
  for (int j0 = 0; j0 < deg; j0 += 64) {
    int j = j0 + lane;
    float e[8];
    if (j < deg) {
      int s = csr[r0 + j];
      const float4* ap = (const float4*)&as_[(long)s * 8];
      float4 a = ap[0], b = ap[1];
      e[0] = LRELU(a.x + da.x); e[1] = LRELU(a.y + da.y);
      e[2] = LRELU(a.z + da.z); e[3] = LRELU(a.w + da.w);
      e[4] = LRELU(b.x + db.x); e[5] = LRELU(b.y + db.y);
      e[6] = LRELU(b.z + db.z); e[7] = LRELU(b.w + db.w);
    } else {
#pragma unroll
      for (int h = 0; h < 8; ++h) e[h] = NEG_BIG;
    }
    if (j0 == 0) {
#pragma unroll
      for (int h = 0; h < 8; ++h) e0[h] = e[h];
    }
#pragma unroll
    for (int h = 0; h < 8; ++h) em[h] = fmaxf(em[h], e[h]);
  }
#pragma unroll
  for (int h = 0; h < 8; ++h) {
#pragma unroll
    for (int ofs = 32; ofs >= 1; ofs >>= 1) em[h] = fmaxf(em[h], __shfl_xor(em[h], ofs));
  }

  // pass 2: sum of exp
  float sm[8];
#pragma unroll
  for (int h = 0; h < 8; ++h) sm[h] = __expf(e0[h] - em[h]);  // invalid lanes -> 0
  for (int j0 = 64; j0 < deg; j0 += 64) {
    int j = j0 + lane;
    if (j < deg) {
      int s = csr[r0 + j];
      const float4* ap = (const float4*)&as_[(long)s * 8];
      float4 a = ap[0], b = ap[1];
      float e[8];
      e[0] = LRELU(a.x + da.x); e[1] = LRELU(a.y + da.y);
      e[2] = LRELU(a.z + da.z); e[3] = LRELU(a.w + da.w);
      e[4] = LRELU(b.x + db.x); e[5] = LRELU(b.y + db.y);
      e[6] = LRELU(b.z + db.z); e[7] = LRELU(b.w + db.w);
#pragma unroll
      for (int h = 0; h < 8; ++h) sm[h] += __expf(e[h] - em[h]);
    }
  }
#pragma unroll
  for (int h = 0; h < 8; ++h) {
#pragma unroll
    for (int ofs = 32; ofs >= 1; ofs >>= 1) sm[h] += __shfl_xor(sm[h], ofs);
  }

  // pass 3: lanes = 64 output cols
  const int h = lane >> 3;
  float Mh = em[0], Sh = sm[0];
#pragma unroll
  for (int q = 1; q < 8; ++q) {
    if (h == q) { Mh = em[q]; Sh = sm[q]; }
  }
  float adv;
  {
    float tmp[8] = {da.x, da.y, da.z, da.w, db.x, db.y, db.z, db.w};
    adv = tmp[0];
#pragma unroll
    for (int q = 1; q < 8; ++q)
      if (h == q) adv = tmp[q];
  }
  const float inv = 1.f / (Sh + 1e-16f);
  float acc = 0.f;
  for (int j = 0; j < deg; ++j) {
    int s = csr[r0 + j];
    float e = LRELU(as_[(long)s * 8 + h] + adv);
    float alpha = __expf(e - Mh) * inv;
    acc += alpha * h1[(long)s * 64 + lane];
  }
  float v = acc + b1[lane];
  h1b[(long)d * 64 + lane] = v > 0.f ? v : __expf(v) - 1.f;
}

// h2[N,16] = h1b[N,64] @ W2[64,16]
__global__ __launch_bounds__(256) void k_gemm2(const float* __restrict__ h1b,
                                               const float* __restrict__ W2,
                                               float* __restrict__ h2, int N) {
  __shared__ float sW[64][16];
  __shared__ float sX[16][64];
  const int t = threadIdx.x;
  const int n0 = blockIdx.x * 16;
  for (int i = t; i < 64 * 16; i += 256) sW[i >> 4][i & 15] = W2[i];
  for (int i = t; i < 16 * 64; i += 256) {
    int r = i >> 6, c = i & 63;
    int n = n0 + r;
    sX[r][c] = (n < N) ? h1b[(long)n * 64 + c] : 0.f;
  }
  __syncthreads();
  int c = t & 15, r = t >> 4;
  float acc = 0.f;
#pragma unroll
  for (int k = 0; k < 64; ++k) acc += sX[r][k] * sW[k][c];
  int n = n0 + r;
  if (n < N) h2[(long)n * 16 + c] = acc;
}

__global__ __launch_bounds__(256) void k_attn2(const float* __restrict__ h2,
                                               const float* __restrict__ attS,
                                               const float* __restrict__ attD,
                                               float* __restrict__ a_s,
                                               float* __restrict__ a_d, int N) {
  int n = blockIdx.x * 256 + threadIdx.x;
  if (n >= N) return;
  const float4* hp = (const float4*)&h2[(long)n * 16];
  float ss = 0.f, dd = 0.f;
#pragma unroll
  for (int q = 0; q < 4; ++q) {
    float4 v = hp[q];
    float4 sv = ((const float4*)attS)[q];
    float4 dv = ((const float4*)attD)[q];
    ss += v.x * sv.x + v.y * sv.y + v.z * sv.z + v.w * sv.w;
    dd += v.x * dv.x + v.y * dv.y + v.z * dv.z + v.w * dv.w;
  }
  a_s[n] = ss;
  a_d[n] = dd;
}

// one wave per dst: softmax + aggregate 16 cols (quarter-waves) + bias + log_softmax
__global__ __launch_bounds__(256) void k_fused2(const int* __restrict__ csr,
                                                const int* __restrict__ off,
                                                const float* __restrict__ as_,
                                                const float* __restrict__ ad_,
                                                const float* __restrict__ h2,
                                                const float* __restrict__ b2,
                                                float* __restrict__ out, int N) {
  int wave = (blockIdx.x * 256 + threadIdx.x) >> 6;
  if (wave >= N) return;
  const int lane = threadIdx.x & 63;
  const int d = wave;
  const int r0 = off[d];
  const int deg = off[d + 1] - r0;
  const float add = ad_[d];

  float em = NEG_BIG, e0 = NEG_BIG;
  for (int j0 = 0; j0 < deg; j0 += 64) {
    int j = j0 + lane;
    float e = NEG_BIG;
    if (j < deg) e = LRELU(as_[csr[r0 + j]] + add);
    if (j0 == 0) e0 = e;
    em = fmaxf(em, e);
  }
#pragma unroll
  for (int ofs = 32; ofs >= 1; ofs >>= 1) em = fmaxf(em, __shfl_xor(em, ofs));

  float sm = (deg > 0) ? __expf(e0 - em) : 0.f;
  for (int j0 = 64; j0 < deg; j0 += 64) {
    int j = j0 + lane;
    if (j < deg) sm += __expf(LRELU(as_[csr[r0 + j]] + add) - em);
  }
#pragma unroll
  for (int ofs = 32; ofs >= 1; ofs >>= 1) sm += __shfl_xor(sm, ofs);
  const float inv = 1.f / (sm + 1e-16f);

  const int sub = lane >> 4, col = lane & 15;
  float acc = 0.f;
  for (int j = sub; j < deg; j += 4) {
    int s = csr[r0 + j];
    float e = LRELU(as_[s] + add);
    float alpha = __expf(e - em) * inv;
    acc += alpha * h2[(long)s * 16 + col];
  }
  acc += __shfl_xor(acc, 16);
  acc += __shfl_xor(acc, 32);

  float v = acc + b2[col];
  float mm = v;
#pragma unroll
  for (int ofs = 1; ofs < 16; ofs <<= 1) mm = fmaxf(mm, __shfl_xor(mm, ofs));
  float ex = __expf(v - mm), ssum = ex;
#pragma unroll
  for (int ofs = 1; ofs < 16; ofs <<= 1) ssum += __shfl_xor(ssum, ofs);
  if (sub == 0) out[(long)d * 16 + col] = v - (mm + __logf(ssum));
}

extern "C" void kernel_launch(void* const* d_in, const int* in_sizes, int n_in,
                              void* d_out, int out_size, void* d_ws, size_t ws_size,
                              hipStream_t stream) {
  const float* x = (const float*)d_in[0];
  const int* ei = (const int*)d_in[1];
  const float* W1 = (const float*)d_in[2];
  const float* attS1 = (const float*)d_in[3];
  const float* attD1 = (const float*)d_in[4];
  const float* b1 = (const float*)d_in[5];
  const float* W2 = (const float*)d_in[6];
  const float* attS2 = (const float*)d_in[7];
  const float* attD2 = (const float*)d_in[8];
  const float* b2 = (const float*)d_in[9];
  float* out = (float*)d_out;

  const int N = in_sizes[0] / 256;
  const int E = in_sizes[1] / 2;

  // ws layout (float offsets):
  // [0,64N): h1; after k_fused1 dead -> h2[16N) at 0, as2 at 16N, ad2 at 17N
  // [64N,128N): h1b
  // [128N,144N): csr (int)
  // [144N,145N+1): off (int)
  // [146N,147N): deg (int)
  // [147N,148N): cursor (int)
  // [148N,149N): scan partials (int)
  float* ws = (float*)d_ws;
  float* h1 = ws;
  float* h1b = ws + (long)64 * N;
  int* csr = (int*)(ws + (long)128 * N);
  int* off = (int*)(ws + (long)144 * N);
  int* deg = (int*)(ws + (long)146 * N);
  int* cursor = (int*)(ws + (long)147 * N);
  int* part = (int*)(ws + (long)148 * N);

  float* h2 = ws;
  float* as2 = ws + (long)16 * N;
  float* ad2 = ws + (long)17 * N;

  // a_s1/a_d1 live in d_out (dead before the final write)
  float* as1 = out;
  float* ad1 = out + (long)8 * N;

  const int EB = (E + 255) / 256;
  const int NB = (N + SCAN_CHUNK - 1) / SCAN_CHUNK;  // 98 scan blocks

  // CSR build
  k_zero_i<<<512, 256, 0, stream>>>(deg, N);
  k_deg<<<EB, 256, 0, stream>>>(ei, deg, E);
  k_scan_part<<<NB, 256, 0, stream>>>(deg, part, N);
  k_scan_top<<<1, 256, 0, stream>>>(part, NB);
  k_scan_final<<<NB, 256, 0, stream>>>(deg, part, off, cursor, N, E);
  k_scatter<<<EB, 256, 0, stream>>>(ei, cursor, csr, E);

  // layer 1
  k_gemm1<<<(N + 31) / 32, 256, 0, stream>>>(x, W1, h1, N);
  k_attn1<<<(N * 8 + 255) / 256, 256, 0, stream>>>(h1, attS1, attD1, as1, ad1, N);
  k_fused1<<<(N + 3) / 4, 256, 0, stream>>>(csr, off, as1, ad1, h1, b1, h1b, N);

  // layer 2
  k_gemm2<<<(N + 15) / 16, 256, 0, stream>>>(h1b, W2, h2, N);
  k_attn2<<<(N + 255) / 256, 256, 0, stream>>>(h2, attS2, attD2, as2, ad2, N);
  k_fused2<<<(N + 3) / 4, 256, 0, stream>>>(csr, off, as2, ad2, h2, b2, out, N);
}

// Round 4
// 513.952 us; speedup vs baseline: 3.7401x; 1.1621x over previous
//
#include <hip/hip_runtime.h>

// GAT 2-layer forward, CSR-based, parallel scan, unrolled gather loops.
// N=100000, E=1.6M, F_in=256, L1: 8 heads x 8 = 64, L2: 1 head x 16.

#define LRELU(v) ((v) > 0.f ? (v) : 0.2f * (v))
#define NEG_BIG -3.4e38f
#define SCAN_CHUNK 1024

__global__ __launch_bounds__(256) void k_zero_i(int* __restrict__ p, int n) {
  int i = blockIdx.x * 256 + threadIdx.x;
  int stride = gridDim.x * 256;
  for (; i < n; i += stride) p[i] = 0;
}

__global__ __launch_bounds__(256) void k_deg(const int* __restrict__ ei, int* __restrict__ deg,
                                             int E) {
  int e = blockIdx.x * 256 + threadIdx.x;
  if (e >= E) return;
  atomicAdd(&deg[ei[E + e]], 1);
}

__global__ __launch_bounds__(256) void k_scan_part(const int* __restrict__ deg,
                                                   int* __restrict__ part, int N) {
  __shared__ int sm[256];
  const int t = threadIdx.x;
  const int base = blockIdx.x * SCAN_CHUNK + t * 4;
  int s = 0;
#pragma unroll
  for (int q = 0; q < 4; ++q) {
    int i = base + q;
    if (i < N) s += deg[i];
  }
  sm[t] = s;
  __syncthreads();
  for (int ofs = 128; ofs >= 1; ofs >>= 1) {
    if (t < ofs) sm[t] += sm[t + ofs];
    __syncthreads();
  }
  if (t == 0) part[blockIdx.x] = sm[0];
}

__global__ __launch_bounds__(256) void k_scan_top(int* __restrict__ part, int nb) {
  __shared__ int sm[256];
  const int t = threadIdx.x;
  sm[t] = (t < nb) ? part[t] : 0;
  __syncthreads();
  for (int ofs = 1; ofs < 256; ofs <<= 1) {
    int v = (t >= ofs) ? sm[t - ofs] : 0;
    __syncthreads();
    sm[t] += v;
    __syncthreads();
  }
  if (t < nb) part[t] = (t > 0) ? sm[t - 1] : 0;
}

__global__ __launch_bounds__(256) void k_scan_final(const int* __restrict__ deg,
                                                    const int* __restrict__ part,
                                                    int* __restrict__ off,
                                                    int* __restrict__ cursor, int N, int E) {
  __shared__ int sm[256];
  const int t = threadIdx.x;
  const int base = blockIdx.x * SCAN_CHUNK + t * 4;
  int d[4];
  int s = 0;
#pragma unroll
  for (int q = 0; q < 4; ++q) {
    int i = base + q;
    d[q] = (i < N) ? deg[i] : 0;
    s += d[q];
  }
  sm[t] = s;
  __syncthreads();
  for (int ofs = 1; ofs < 256; ofs <<= 1) {
    int v = (t >= ofs) ? sm[t - ofs] : 0;
    __syncthreads();
    sm[t] += v;
    __syncthreads();
  }
  int run = part[blockIdx.x] + ((t > 0) ? sm[t - 1] : 0);
#pragma unroll
  for (int q = 0; q < 4; ++q) {
    int i = base + q;
    if (i < N) {
      off[i] = run;
      cursor[i] = run;
      run += d[q];
    }
  }
  if (blockIdx.x == 0 && t == 0) off[N] = E;
}

__global__ __launch_bounds__(256) void k_scatter(const int* __restrict__ ei,
                                                 int* __restrict__ cursor,
                                                 int* __restrict__ csr, int E) {
  int e = blockIdx.x * 256 + threadIdx.x;
  if (e >= E) return;
  int d = ei[E + e];
  int p = atomicAdd(&cursor[d], 1);
  csr[p] = ei[e];
}

// h1[N,64] = x[N,256] @ W1[256,64]
__global__ __launch_bounds__(256) void k_gemm1(const float* __restrict__ x,
                                               const float* __restrict__ W,
                                               float* __restrict__ h1, int N) {
  __shared__ float sX[32][256];
  const int t = threadIdx.x;
  const int n0 = blockIdx.x * 32;
  for (int i = t; i < 32 * 256; i += 256) {
    int r = i >> 8, c = i & 255;
    int n = n0 + r;
    sX[r][c] = (n < N) ? x[(long)n * 256 + c] : 0.f;
  }
  __syncthreads();
  const int col = t & 63;
  const int rg = t >> 6;
  float acc[8];
#pragma unroll
  for (int i = 0; i < 8; ++i) acc[i] = 0.f;
  for (int kk = 0; kk < 256; kk += 4) {
    float w0 = W[(kk + 0) * 64 + col];
    float w1 = W[(kk + 1) * 64 + col];
    float w2 = W[(kk + 2) * 64 + col];
    float w3 = W[(kk + 3) * 64 + col];
#pragma unroll
    for (int rr = 0; rr < 8; ++rr) {
      const float4 xv = *(const float4*)&sX[rg * 8 + rr][kk];
      acc[rr] += xv.x * w0 + xv.y * w1 + xv.z * w2 + xv.w * w3;
    }
  }
#pragma unroll
  for (int rr = 0; rr < 8; ++rr) {
    int n = n0 + rg * 8 + rr;
    if (n < N) h1[(long)n * 64 + col] = acc[rr];
  }
}

__global__ __launch_bounds__(256) void k_attn1(const float* __restrict__ h1,
                                               const float* __restrict__ attS,
                                               const float* __restrict__ attD,
                                               float* __restrict__ a_s,
                                               float* __restrict__ a_d, int N) {
  int i = blockIdx.x * 256 + threadIdx.x;  // i = n*8 + h
  if (i >= N * 8) return;
  int h = i & 7;
  const float4* hp = (const float4*)&h1[(long)i * 8];
  float4 v0 = hp[0], v1 = hp[1];
  const float4* s0 = (const float4*)&attS[h * 8];
  const float4* d0 = (const float4*)&attD[h * 8];
  float4 sa = s0[0], sb = s0[1], da = d0[0], db = d0[1];
  a_s[i] = v0.x * sa.x + v0.y * sa.y + v0.z * sa.z + v0.w * sa.w +
           v1.x * sb.x + v1.y * sb.y + v1.z * sb.z + v1.w * sb.w;
  a_d[i] = v0.x * da.x + v0.y * da.y + v0.z * da.z + v0.w * da.w +
           v1.x * db.x + v1.y * db.y + v1.z * db.z + v1.w * db.w;
}

// one wave per dst node: segment softmax (8 heads) + aggregate 64 cols + bias + ELU
__global__ __launch_bounds__(256) void k_fused1(const int* __restrict__ csr,
                                                const int* __restrict__ off,
                                                const float* __restrict__ as_,
                                                const float* __restrict__ ad_,
                                                const float* __restrict__ h1,
                                                const float* __restrict__ b1,
                                                float* __restrict__ h1b, int N) {
  int wave = (blockIdx.x * 256 + threadIdx.x) >> 6;
  if (wave >= N) return;
  const int lane = threadIdx.x & 63;
  const int d = wave;
  const int r0 = off[d];
  const int deg = off[d + 1] - r0;

  if (deg == 0) {
    float v = b1[lane];
    h1b[(long)d * 64 + lane] = v > 0.f ? v : __expf(v) - 1.f;
    return;
  }

  const float4* dp = (const float4*)&ad_[(long)d * 8];
  float4 da = dp[0], db = dp[1];

  // pass 1: per-lane max; keep first chunk's e in regs
  float em[8], e0[8];
#pragma unroll
  for (int h = 0; h < 8; ++h) em[h] = NEG_BIG;
  for (int j0 = 0; j0 < deg; j0 += 64) {
    int j = j0 + lane;
    float e[8];
    if (j < deg) {
      int s = csr[r0 + j];
      const float4* ap = (const float4*)&as_[(long)s * 8];
      float4 a = ap[0], b = ap[1];
      e[0] = LRELU(a.x + da.x); e[1] = LRELU(a.y + da.y);
      e[2] = LRELU(a.z + da.z); e[3] = LRELU(a.w + da.w);
      e[4] = LRELU(b.x + db.x); e[5] = LRELU(b.y + db.y);
      e[6] = LRELU(b.z + db.z); e[7] = LRELU(b.w + db.w);
    } else {
#pragma unroll
      for (int h = 0; h < 8; ++h) e[h] = NEG_BIG;
    }
    if (j0 == 0) {
#pragma unroll
      for (int h = 0; h < 8; ++h) e0[h] = e[h];
    }
#pragma unroll
    for (int h = 0; h < 8; ++h) em[h] = fmaxf(em[h], e[h]);
  }
#pragma unroll
  for (int h = 0; h < 8; ++h) {
#pragma unroll
    for (int ofs = 32; ofs >= 1; ofs >>= 1) em[h] = fmaxf(em[h], __shfl_xor(em[h], ofs));
  }

  // pass 2: sum of exp
  float sm[8];
#pragma unroll
  for (int h = 0; h < 8; ++h) sm[h] = __expf(e0[h] - em[h]);
  for (int j0 = 64; j0 < deg; j0 += 64) {
    int j = j0 + lane;
    if (j < deg) {
      int s = csr[r0 + j];
      const float4* ap = (const float4*)&as_[(long)s * 8];
      float4 a = ap[0], b = ap[1];
      float e[8];
      e[0] = LRELU(a.x + da.x); e[1] = LRELU(a.y + da.y);
      e[2] = LRELU(a.z + da.z); e[3] = LRELU(a.w + da.w);
      e[4] = LRELU(b.x + db.x); e[5] = LRELU(b.y + db.y);
      e[6] = LRELU(b.z + db.z); e[7] = LRELU(b.w + db.w);
#pragma unroll
      for (int h = 0; h < 8; ++h) sm[h] += __expf(e[h] - em[h]);
    }
  }
#pragma unroll
  for (int h = 0; h < 8; ++h) {
#pragma unroll
    for (int ofs = 32; ofs >= 1; ofs >>= 1) sm[h] += __shfl_xor(sm[h], ofs);
  }

  // pass 3: lanes = 64 output cols, 4x unrolled over edges for MLP
  const int h = lane >> 3;
  float Mh = em[0], Sh = sm[0];
#pragma unroll
  for (int q = 1; q < 8; ++q) {
    if (h == q) { Mh = em[q]; Sh = sm[q]; }
  }
  float adv;
  {
    float tmp[8] = {da.x, da.y, da.z, da.w, db.x, db.y, db.z, db.w};
    adv = tmp[0];
#pragma unroll
    for (int q = 1; q < 8; ++q)
      if (h == q) adv = tmp[q];
  }
  const float inv = 1.f / (Sh + 1e-16f);
  float acc = 0.f;
  int j = 0;
  for (; j + 4 <= deg; j += 4) {
    int s0 = csr[r0 + j], s1 = csr[r0 + j + 1], s2 = csr[r0 + j + 2], s3 = csr[r0 + j + 3];
    float x0 = as_[(long)s0 * 8 + h];
    float x1 = as_[(long)s1 * 8 + h];
    float x2 = as_[(long)s2 * 8 + h];
    float x3 = as_[(long)s3 * 8 + h];
    float f0 = h1[(long)s0 * 64 + lane];
    float f1 = h1[(long)s1 * 64 + lane];
    float f2 = h1[(long)s2 * 64 + lane];
    float f3 = h1[(long)s3 * 64 + lane];
    float u0 = LRELU(x0 + adv), u1 = LRELU(x1 + adv);
    float u2 = LRELU(x2 + adv), u3 = LRELU(x3 + adv);
    acc += __expf(u0 - Mh) * inv * f0;
    acc += __expf(u1 - Mh) * inv * f1;
    acc += __expf(u2 - Mh) * inv * f2;
    acc += __expf(u3 - Mh) * inv * f3;
  }
  for (; j < deg; ++j) {
    int s = csr[r0 + j];
    float e = LRELU(as_[(long)s * 8 + h] + adv);
    acc += __expf(e - Mh) * inv * h1[(long)s * 64 + lane];
  }
  float v = acc + b1[lane];
  h1b[(long)d * 64 + lane] = v > 0.f ? v : __expf(v) - 1.f;
}

// h2[N,16] = h1b[N,64] @ W2[64,16]
__global__ __launch_bounds__(256) void k_gemm2(const float* __restrict__ h1b,
                                               const float* __restrict__ W2,
                                               float* __restrict__ h2, int N) {
  __shared__ float sW[64][16];
  __shared__ float sX[16][64];
  const int t = threadIdx.x;
  const int n0 = blockIdx.x * 16;
  for (int i = t; i < 64 * 16; i += 256) sW[i >> 4][i & 15] = W2[i];
  for (int i = t; i < 16 * 64; i += 256) {
    int r = i >> 6, c = i & 63;
    int n = n0 + r;
    sX[r][c] = (n < N) ? h1b[(long)n * 64 + c] : 0.f;
  }
  __syncthreads();
  int c = t & 15, r = t >> 4;
  float acc = 0.f;
#pragma unroll
  for (int k = 0; k < 64; ++k) acc += sX[r][k] * sW[k][c];
  int n = n0 + r;
  if (n < N) h2[(long)n * 16 + c] = acc;
}

__global__ __launch_bounds__(256) void k_attn2(const float* __restrict__ h2,
                                               const float* __restrict__ attS,
                                               const float* __restrict__ attD,
                                               float* __restrict__ a_s,
                                               float* __restrict__ a_d, int N) {
  int n = blockIdx.x * 256 + threadIdx.x;
  if (n >= N) return;
  const float4* hp = (const float4*)&h2[(long)n * 16];
  float ss = 0.f, dd = 0.f;
#pragma unroll
  for (int q = 0; q < 4; ++q) {
    float4 v = hp[q];
    float4 sv = ((const float4*)attS)[q];
    float4 dv = ((const float4*)attD)[q];
    ss += v.x * sv.x + v.y * sv.y + v.z * sv.z + v.w * sv.w;
    dd += v.x * dv.x + v.y * dv.y + v.z * dv.z + v.w * dv.w;
  }
  a_s[n] = ss;
  a_d[n] = dd;
}

// one wave per dst: softmax + aggregate 16 cols (quarter-waves, 2x unrolled)
__global__ __launch_bounds__(256) void k_fused2(const int* __restrict__ csr,
                                                const int* __restrict__ off,
                                                const float* __restrict__ as_,
                                                const float* __restrict__ ad_,
                                                const float* __restrict__ h2,
                                                const float* __restrict__ b2,
                                                float* __restrict__ out, int N) {
  int wave = (blockIdx.x * 256 + threadIdx.x) >> 6;
  if (wave >= N) return;
  const int lane = threadIdx.x & 63;
  const int d = wave;
  const int r0 = off[d];
  const int deg = off[d + 1] - r0;
  const float add = ad_[d];

  float em = NEG_BIG, e0 = NEG_BIG;
  for (int j0 = 0; j0 < deg; j0 += 64) {
    int j = j0 + lane;
    float e = NEG_BIG;
    if (j < deg) e = LRELU(as_[csr[r0 + j]] + add);
    if (j0 == 0) e0 = e;
    em = fmaxf(em, e);
  }
#pragma unroll
  for (int ofs = 32; ofs >= 1; ofs >>= 1) em = fmaxf(em, __shfl_xor(em, ofs));

  float sm = (deg > 0) ? __expf(e0 - em) : 0.f;
  for (int j0 = 64; j0 < deg; j0 += 64) {
    int j = j0 + lane;
    if (j < deg) sm += __expf(LRELU(as_[csr[r0 + j]] + add) - em);
  }
#pragma unroll
  for (int ofs = 32; ofs >= 1; ofs >>= 1) sm += __shfl_xor(sm, ofs);
  const float inv = 1.f / (sm + 1e-16f);

  const int sub = lane >> 4, col = lane & 15;
  float acc = 0.f;
  int j = sub;
  for (; j + 4 < deg; j += 8) {
    int s0 = csr[r0 + j], s1 = csr[r0 + j + 4];
    float x0 = as_[s0], x1 = as_[s1];
    float f0 = h2[(long)s0 * 16 + col], f1 = h2[(long)s1 * 16 + col];
    float u0 = LRELU(x0 + add), u1 = LRELU(x1 + add);
    acc += __expf(u0 - em) * inv * f0 + __expf(u1 - em) * inv * f1;
  }
  for (; j < deg; j += 4) {
    int s = csr[r0 + j];
    float e = LRELU(as_[s] + add);
    acc += __expf(e - em) * inv * h2[(long)s * 16 + col];
  }
  acc += __shfl_xor(acc, 16);
  acc += __shfl_xor(acc, 32);

  float v = acc + b2[col];
  float mm = v;
#pragma unroll
  for (int ofs = 1; ofs < 16; ofs <<= 1) mm = fmaxf(mm, __shfl_xor(mm, ofs));
  float ex = __expf(v - mm), ssum = ex;
#pragma unroll
  for (int ofs = 1; ofs < 16; ofs <<= 1) ssum += __shfl_xor(ssum, ofs);
  if (sub == 0) out[(long)d * 16 + col] = v - (mm + __logf(ssum));
}

extern "C" void kernel_launch(void* const* d_in, const int* in_sizes, int n_in,
                              void* d_out, int out_size, void* d_ws, size_t ws_size,
                              hipStream_t stream) {
  const float* x = (const float*)d_in[0];
  const int* ei = (const int*)d_in[1];
  const float* W1 = (const float*)d_in[2];
  const float* attS1 = (const float*)d_in[3];
  const float* attD1 = (const float*)d_in[4];
  const float* b1 = (const float*)d_in[5];
  const float* W2 = (const float*)d_in[6];
  const float* attS2 = (const float*)d_in[7];
  const float* attD2 = (const float*)d_in[8];
  const float* b2 = (const float*)d_in[9];
  float* out = (float*)d_out;

  const int N = in_sizes[0] / 256;
  const int E = in_sizes[1] / 2;

  float* ws = (float*)d_ws;
  float* h1 = ws;
  float* h1b = ws + (long)64 * N;
  int* csr = (int*)(ws + (long)128 * N);
  int* off = (int*)(ws + (long)144 * N);
  int* deg = (int*)(ws + (long)146 * N);
  int* cursor = (int*)(ws + (long)147 * N);
  int* part = (int*)(ws + (long)148 * N);

  float* h2 = ws;
  float* as2 = ws + (long)16 * N;
  float* ad2 = ws + (long)17 * N;

  float* as1 = out;
  float* ad1 = out + (long)8 * N;

  const int EB = (E + 255) / 256;
  const int NB = (N + SCAN_CHUNK - 1) / SCAN_CHUNK;

  k_zero_i<<<512, 256, 0, stream>>>(deg, N);
  k_deg<<<EB, 256, 0, stream>>>(ei, deg, E);
  k_scan_part<<<NB, 256, 0, stream>>>(deg, part, N);
  k_scan_top<<<1, 256, 0, stream>>>(part, NB);
  k_scan_final<<<NB, 256, 0, stream>>>(deg, part, off, cursor, N, E);
  k_scatter<<<EB, 256, 0, stream>>>(ei, cursor, csr, E);

  k_gemm1<<<(N + 31) / 32, 256, 0, stream>>>(x, W1, h1, N);
  k_attn1<<<(N * 8 + 255) / 256, 256, 0, stream>>>(h1, attS1, attD1, as1, ad1, N);
  k_fused1<<<(N + 3) / 4, 256, 0, stream>>>(csr, off, as1, ad1, h1, b1, h1b, N);

  k_gemm2<<<(N + 15) / 16, 256, 0, stream>>>(h1b, W2, h2, N);
  k_attn2<<<(N + 255) / 256, 256, 0, stream>>>(h2, attS2, attD2, as2, ad2, N);
  k_fused2<<<(N + 3) / 4, 256, 0, stream>>>(csr, off, as2, ad2, h2, b2, out, N);
}

// Round 5
// 470.782 us; speedup vs baseline: 4.0830x; 1.0917x over previous
//
#include <hip/hip_runtime.h>

// GAT 2-layer forward, CSR-based, parallel scan, register-tiled GEMM1+attn fusion.
// N=100000, E=1.6M, F_in=256, L1: 8 heads x 8 = 64, L2: 1 head x 16.

#define LRELU(v) ((v) > 0.f ? (v) : 0.2f * (v))
#define NEG_BIG -3.4e38f
#define SCAN_CHUNK 1024

__global__ __launch_bounds__(256) void k_zero_i(int* __restrict__ p, int n) {
  int i = blockIdx.x * 256 + threadIdx.x;
  int stride = gridDim.x * 256;
  for (; i < n; i += stride) p[i] = 0;
}

__global__ __launch_bounds__(256) void k_deg(const int* __restrict__ ei, int* __restrict__ deg,
                                             int E) {
  int e = blockIdx.x * 256 + threadIdx.x;
  if (e >= E) return;
  atomicAdd(&deg[ei[E + e]], 1);
}

__global__ __launch_bounds__(256) void k_scan_part(const int* __restrict__ deg,
                                                   int* __restrict__ part, int N) {
  __shared__ int sm[256];
  const int t = threadIdx.x;
  const int base = blockIdx.x * SCAN_CHUNK + t * 4;
  int s = 0;
#pragma unroll
  for (int q = 0; q < 4; ++q) {
    int i = base + q;
    if (i < N) s += deg[i];
  }
  sm[t] = s;
  __syncthreads();
  for (int ofs = 128; ofs >= 1; ofs >>= 1) {
    if (t < ofs) sm[t] += sm[t + ofs];
    __syncthreads();
  }
  if (t == 0) part[blockIdx.x] = sm[0];
}

__global__ __launch_bounds__(256) void k_scan_top(int* __restrict__ part, int nb) {
  __shared__ int sm[256];
  const int t = threadIdx.x;
  sm[t] = (t < nb) ? part[t] : 0;
  __syncthreads();
  for (int ofs = 1; ofs < 256; ofs <<= 1) {
    int v = (t >= ofs) ? sm[t - ofs] : 0;
    __syncthreads();
    sm[t] += v;
    __syncthreads();
  }
  if (t < nb) part[t] = (t > 0) ? sm[t - 1] : 0;
}

__global__ __launch_bounds__(256) void k_scan_final(const int* __restrict__ deg,
                                                    const int* __restrict__ part,
                                                    int* __restrict__ off,
                                                    int* __restrict__ cursor, int N, int E) {
  __shared__ int sm[256];
  const int t = threadIdx.x;
  const int base = blockIdx.x * SCAN_CHUNK + t * 4;
  int d[4];
  int s = 0;
#pragma unroll
  for (int q = 0; q < 4; ++q) {
    int i = base + q;
    d[q] = (i < N) ? deg[i] : 0;
    s += d[q];
  }
  sm[t] = s;
  __syncthreads();
  for (int ofs = 1; ofs < 256; ofs <<= 1) {
    int v = (t >= ofs) ? sm[t - ofs] : 0;
    __syncthreads();
    sm[t] += v;
    __syncthreads();
  }
  int run = part[blockIdx.x] + ((t > 0) ? sm[t - 1] : 0);
#pragma unroll
  for (int q = 0; q < 4; ++q) {
    int i = base + q;
    if (i < N) {
      off[i] = run;
      cursor[i] = run;
      run += d[q];
    }
  }
  if (blockIdx.x == 0 && t == 0) off[N] = E;
}

__global__ __launch_bounds__(256) void k_scatter(const int* __restrict__ ei,
                                                 int* __restrict__ cursor,
                                                 int* __restrict__ csr, int E) {
  int e = blockIdx.x * 256 + threadIdx.x;
  if (e >= E) return;
  int d = ei[E + e];
  int p = atomicAdd(&cursor[d], 1);
  csr[p] = ei[e];
}

// h1[N,64] = x[N,256] @ W1[256,64], fused a_s/a_d epilogue.
// 64x64 tile, 16x16 threads, 4x4 acc per thread. LDS: xT chunk + W chunk.
__global__ __launch_bounds__(256) void k_gemm1(const float* __restrict__ x,
                                               const float* __restrict__ W,
                                               const float* __restrict__ attS,
                                               const float* __restrict__ attD,
                                               float* __restrict__ h1,
                                               float* __restrict__ a_s,
                                               float* __restrict__ a_d, int N) {
  __shared__ float sA[64][68];  // sA[k][row], stride 68 floats: 16B-aligned float4 reads
  __shared__ float sW[64][64];  // sW[k][col]
  const int t = threadIdx.x;
  const int n0 = blockIdx.x * 64;
  const int tr = t >> 4, tc = t & 15;
  const int tr4 = tr * 4, tc4 = tc * 4;

  float acc[4][4];
#pragma unroll
  for (int i = 0; i < 4; ++i)
#pragma unroll
    for (int j = 0; j < 4; ++j) acc[i][j] = 0.f;

  for (int c0 = 0; c0 < 256; c0 += 64) {
    // stage x^T chunk: thread loads 16 consecutive k for one row
    {
      const int r = t >> 2, kq = (t & 3) * 16;
      const int n = n0 + r;
      float4 v[4];
      if (n < N) {
        const float4* xp = (const float4*)&x[(long)n * 256 + c0 + kq];
#pragma unroll
        for (int q = 0; q < 4; ++q) v[q] = xp[q];
      } else {
#pragma unroll
        for (int q = 0; q < 4; ++q) v[q] = make_float4(0.f, 0.f, 0.f, 0.f);
      }
#pragma unroll
      for (int q = 0; q < 4; ++q) {
        sA[kq + q * 4 + 0][r] = v[q].x;
        sA[kq + q * 4 + 1][r] = v[q].y;
        sA[kq + q * 4 + 2][r] = v[q].z;
        sA[kq + q * 4 + 3][r] = v[q].w;
      }
    }
    // stage W chunk
#pragma unroll
    for (int i = 0; i < 4; ++i) {
      int idx = t + i * 256;
      int k = idx >> 4, col4 = (idx & 15) * 4;
      *(float4*)&sW[k][col4] = *(const float4*)&W[(long)(c0 + k) * 64 + col4];
    }
    __syncthreads();
#pragma unroll 16
    for (int k = 0; k < 64; ++k) {
      const float4 a = *(const float4*)&sA[k][tr4];
      const float4 b = *(const float4*)&sW[k][tc4];
      acc[0][0] += a.x * b.x; acc[0][1] += a.x * b.y; acc[0][2] += a.x * b.z; acc[0][3] += a.x * b.w;
      acc[1][0] += a.y * b.x; acc[1][1] += a.y * b.y; acc[1][2] += a.y * b.z; acc[1][3] += a.y * b.w;
      acc[2][0] += a.z * b.x; acc[2][1] += a.z * b.y; acc[2][2] += a.z * b.z; acc[2][3] += a.z * b.w;
      acc[3][0] += a.w * b.x; acc[3][1] += a.w * b.y; acc[3][2] += a.w * b.z; acc[3][3] += a.w * b.w;
    }
    __syncthreads();
  }

  // epilogue: store h1 + fused attn dot-products.
  // thread's 4 cols (4tc..4tc+3) lie in single head = tc>>1; pair-reduce via shfl_xor(1).
  const int head = tc >> 1;
  float attSv[4], attDv[4];
#pragma unroll
  for (int j = 0; j < 4; ++j) {
    int c7 = (tc4 + j) & 7;
    attSv[j] = attS[head * 8 + c7];
    attDv[j] = attD[head * 8 + c7];
  }
#pragma unroll
  for (int i = 0; i < 4; ++i) {
    const int n = n0 + tr4 + i;
    float ps = acc[i][0] * attSv[0] + acc[i][1] * attSv[1] + acc[i][2] * attSv[2] +
               acc[i][3] * attSv[3];
    float pd = acc[i][0] * attDv[0] + acc[i][1] * attDv[1] + acc[i][2] * attDv[2] +
               acc[i][3] * attDv[3];
    ps += __shfl_xor(ps, 1);
    pd += __shfl_xor(pd, 1);
    if (n < N) {
      *(float4*)&h1[(long)n * 64 + tc4] =
          make_float4(acc[i][0], acc[i][1], acc[i][2], acc[i][3]);
      if ((tc & 1) == 0) {
        a_s[n * 8 + head] = ps;
        a_d[n * 8 + head] = pd;
      }
    }
  }
}

// one wave per dst node: segment softmax (8 heads) + aggregate 64 cols + bias + ELU
__global__ __launch_bounds__(256) void k_fused1(const int* __restrict__ csr,
                                                const int* __restrict__ off,
                                                const float* __restrict__ as_,
                                                const float* __restrict__ ad_,
                                                const float* __restrict__ h1,
                                                const float* __restrict__ b1,
                                                float* __restrict__ h1b, int N) {
  int wave = (blockIdx.x * 256 + threadIdx.x) >> 6;
  if (wave >= N) return;
  const int lane = threadIdx.x & 63;
  const int d = wave;
  const int r0 = off[d];
  const int deg = off[d + 1] - r0;

  if (deg == 0) {
    float v = b1[lane];
    h1b[(long)d * 64 + lane] = v > 0.f ? v : __expf(v) - 1.f;
    return;
  }

  const float4* dp = (const float4*)&ad_[(long)d * 8];
  float4 da = dp[0], db = dp[1];

  // pass 1: per-lane max; keep first chunk's e in regs
  float em[8], e0[8];
#pragma unroll
  for (int h = 0; h < 8; ++h) em[h] = NEG_BIG;
  for (int j0 = 0; j0 < deg; j0 += 64) {
    int j = j0 + lane;
    float e[8];
    if (j < deg) {
      int s = csr[r0 + j];
      const float4* ap = (const float4*)&as_[(long)s * 8];
      float4 a = ap[0], b = ap[1];
      e[0] = LRELU(a.x + da.x); e[1] = LRELU(a.y + da.y);
      e[2] = LRELU(a.z + da.z); e[3] = LRELU(a.w + da.w);
      e[4] = LRELU(b.x + db.x); e[5] = LRELU(b.y + db.y);
      e[6] = LRELU(b.z + db.z); e[7] = LRELU(b.w + db.w);
    } else {
#pragma unroll
      for (int h = 0; h < 8; ++h) e[h] = NEG_BIG;
    }
    if (j0 == 0) {
#pragma unroll
      for (int h = 0; h < 8; ++h) e0[h] = e[h];
    }
#pragma unroll
    for (int h = 0; h < 8; ++h) em[h] = fmaxf(em[h], e[h]);
  }
#pragma unroll
  for (int h = 0; h < 8; ++h) {
#pragma unroll
    for (int ofs = 32; ofs >= 1; ofs >>= 1) em[h] = fmaxf(em[h], __shfl_xor(em[h], ofs));
  }

  // pass 2: sum of exp
  float sm[8];
#pragma unroll
  for (int h = 0; h < 8; ++h) sm[h] = __expf(e0[h] - em[h]);
  for (int j0 = 64; j0 < deg; j0 += 64) {
    int j = j0 + lane;
    if (j < deg) {
      int s = csr[r0 + j];
      const float4* ap = (const float4*)&as_[(long)s * 8];
      float4 a = ap[0], b = ap[1];
      float e[8];
      e[0] = LRELU(a.x + da.x); e[1] = LRELU(a.y + da.y);
      e[2] = LRELU(a.z + da.z); e[3] = LRELU(a.w + da.w);
      e[4] = LRELU(b.x + db.x); e[5] = LRELU(b.y + db.y);
      e[6] = LRELU(b.z + db.z); e[7] = LRELU(b.w + db.w);
#pragma unroll
      for (int h = 0; h < 8; ++h) sm[h] += __expf(e[h] - em[h]);
    }
  }
#pragma unroll
  for (int h = 0; h < 8; ++h) {
#pragma unroll
    for (int ofs = 32; ofs >= 1; ofs >>= 1) sm[h] += __shfl_xor(sm[h], ofs);
  }

  // pass 3: lanes = 64 output cols, 4x unrolled over edges for MLP
  const int h = lane >> 3;
  float Mh = em[0], Sh = sm[0];
#pragma unroll
  for (int q = 1; q < 8; ++q) {
    if (h == q) { Mh = em[q]; Sh = sm[q]; }
  }
  float adv;
  {
    float tmp[8] = {da.x, da.y, da.z, da.w, db.x, db.y, db.z, db.w};
    adv = tmp[0];
#pragma unroll
    for (int q = 1; q < 8; ++q)
      if (h == q) adv = tmp[q];
  }
  const float inv = 1.f / (Sh + 1e-16f);
  float acc = 0.f;
  int j = 0;
  for (; j + 4 <= deg; j += 4) {
    int s0 = csr[r0 + j], s1 = csr[r0 + j + 1], s2 = csr[r0 + j + 2], s3 = csr[r0 + j + 3];
    float x0 = as_[(long)s0 * 8 + h];
    float x1 = as_[(long)s1 * 8 + h];
    float x2 = as_[(long)s2 * 8 + h];
    float x3 = as_[(long)s3 * 8 + h];
    float f0 = h1[(long)s0 * 64 + lane];
    float f1 = h1[(long)s1 * 64 + lane];
    float f2 = h1[(long)s2 * 64 + lane];
    float f3 = h1[(long)s3 * 64 + lane];
    float u0 = LRELU(x0 + adv), u1 = LRELU(x1 + adv);
    float u2 = LRELU(x2 + adv), u3 = LRELU(x3 + adv);
    acc += __expf(u0 - Mh) * inv * f0;
    acc += __expf(u1 - Mh) * inv * f1;
    acc += __expf(u2 - Mh) * inv * f2;
    acc += __expf(u3 - Mh) * inv * f3;
  }
  for (; j < deg; ++j) {
    int s = csr[r0 + j];
    float e = LRELU(as_[(long)s * 8 + h] + adv);
    acc += __expf(e - Mh) * inv * h1[(long)s * 64 + lane];
  }
  float v = acc + b1[lane];
  h1b[(long)d * 64 + lane] = v > 0.f ? v : __expf(v) - 1.f;
}

// h2[N,16] = h1b[N,64] @ W2[64,16]
__global__ __launch_bounds__(256) void k_gemm2(const float* __restrict__ h1b,
                                               const float* __restrict__ W2,
                                               float* __restrict__ h2, int N) {
  __shared__ float sW[64][16];
  __shared__ float sX[16][64];
  const int t = threadIdx.x;
  const int n0 = blockIdx.x * 16;
  for (int i = t; i < 64 * 16; i += 256) sW[i >> 4][i & 15] = W2[i];
  for (int i = t; i < 16 * 64; i += 256) {
    int r = i >> 6, c = i & 63;
    int n = n0 + r;
    sX[r][c] = (n < N) ? h1b[(long)n * 64 + c] : 0.f;
  }
  __syncthreads();
  int c = t & 15, r = t >> 4;
  float acc = 0.f;
#pragma unroll
  for (int k = 0; k < 64; ++k) acc += sX[r][k] * sW[k][c];
  int n = n0 + r;
  if (n < N) h2[(long)n * 16 + c] = acc;
}

__global__ __launch_bounds__(256) void k_attn2(const float* __restrict__ h2,
                                               const float* __restrict__ attS,
                                               const float* __restrict__ attD,
                                               float* __restrict__ a_s,
                                               float* __restrict__ a_d, int N) {
  int n = blockIdx.x * 256 + threadIdx.x;
  if (n >= N) return;
  const float4* hp = (const float4*)&h2[(long)n * 16];
  float ss = 0.f, dd = 0.f;
#pragma unroll
  for (int q = 0; q < 4; ++q) {
    float4 v = hp[q];
    float4 sv = ((const float4*)attS)[q];
    float4 dv = ((const float4*)attD)[q];
    ss += v.x * sv.x + v.y * sv.y + v.z * sv.z + v.w * sv.w;
    dd += v.x * dv.x + v.y * dv.y + v.z * dv.z + v.w * dv.w;
  }
  a_s[n] = ss;
  a_d[n] = dd;
}

// one wave per dst: softmax + aggregate 16 cols (quarter-waves, 2x unrolled)
__global__ __launch_bounds__(256) void k_fused2(const int* __restrict__ csr,
                                                const int* __restrict__ off,
                                                const float* __restrict__ as_,
                                                const float* __restrict__ ad_,
                                                const float* __restrict__ h2,
                                                const float* __restrict__ b2,
                                                float* __restrict__ out, int N) {
  int wave = (blockIdx.x * 256 + threadIdx.x) >> 6;
  if (wave >= N) return;
  const int lane = threadIdx.x & 63;
  const int d = wave;
  const int r0 = off[d];
  const int deg = off[d + 1] - r0;
  const float add = ad_[d];

  float em = NEG_BIG, e0 = NEG_BIG;
  for (int j0 = 0; j0 < deg; j0 += 64) {
    int j = j0 + lane;
    float e = NEG_BIG;
    if (j < deg) e = LRELU(as_[csr[r0 + j]] + add);
    if (j0 == 0) e0 = e;
    em = fmaxf(em, e);
  }
#pragma unroll
  for (int ofs = 32; ofs >= 1; ofs >>= 1) em = fmaxf(em, __shfl_xor(em, ofs));

  float sm = (deg > 0) ? __expf(e0 - em) : 0.f;
  for (int j0 = 64; j0 < deg; j0 += 64) {
    int j = j0 + lane;
    if (j < deg) sm += __expf(LRELU(as_[csr[r0 + j]] + add) - em);
  }
#pragma unroll
  for (int ofs = 32; ofs >= 1; ofs >>= 1) sm += __shfl_xor(sm, ofs);
  const float inv = 1.f / (sm + 1e-16f);

  const int sub = lane >> 4, col = lane & 15;
  float acc = 0.f;
  int j = sub;
  for (; j + 4 < deg; j += 8) {
    int s0 = csr[r0 + j], s1 = csr[r0 + j + 4];
    float x0 = as_[s0], x1 = as_[s1];
    float f0 = h2[(long)s0 * 16 + col], f1 = h2[(long)s1 * 16 + col];
    float u0 = LRELU(x0 + add), u1 = LRELU(x1 + add);
    acc += __expf(u0 - em) * inv * f0 + __expf(u1 - em) * inv * f1;
  }
  for (; j < deg; j += 4) {
    int s = csr[r0 + j];
    float e = LRELU(as_[s] + add);
    acc += __expf(e - em) * inv * h2[(long)s * 16 + col];
  }
  acc += __shfl_xor(acc, 16);
  acc += __shfl_xor(acc, 32);

  float v = acc + b2[col];
  float mm = v;
#pragma unroll
  for (int ofs = 1; ofs < 16; ofs <<= 1) mm = fmaxf(mm, __shfl_xor(mm, ofs));
  float ex = __expf(v - mm), ssum = ex;
#pragma unroll
  for (int ofs = 1; ofs < 16; ofs <<= 1) ssum += __shfl_xor(ssum, ofs);
  if (sub == 0) out[(long)d * 16 + col] = v - (mm + __logf(ssum));
}

extern "C" void kernel_launch(void* const* d_in, const int* in_sizes, int n_in,
                              void* d_out, int out_size, void* d_ws, size_t ws_size,
                              hipStream_t stream) {
  const float* x = (const float*)d_in[0];
  const int* ei = (const int*)d_in[1];
  const float* W1 = (const float*)d_in[2];
  const float* attS1 = (const float*)d_in[3];
  const float* attD1 = (const float*)d_in[4];
  const float* b1 = (const float*)d_in[5];
  const float* W2 = (const float*)d_in[6];
  const float* attS2 = (const float*)d_in[7];
  const float* attD2 = (const float*)d_in[8];
  const float* b2 = (const float*)d_in[9];
  float* out = (float*)d_out;

  const int N = in_sizes[0] / 256;
  const int E = in_sizes[1] / 2;

  float* ws = (float*)d_ws;
  float* h1 = ws;
  float* h1b = ws + (long)64 * N;
  int* csr = (int*)(ws + (long)128 * N);
  int* off = (int*)(ws + (long)144 * N);
  int* deg = (int*)(ws + (long)146 * N);
  int* cursor = (int*)(ws + (long)147 * N);
  int* part = (int*)(ws + (long)148 * N);

  float* h2 = ws;
  float* as2 = ws + (long)16 * N;
  float* ad2 = ws + (long)17 * N;

  float* as1 = out;
  float* ad1 = out + (long)8 * N;

  const int EB = (E + 255) / 256;
  const int NB = (N + SCAN_CHUNK - 1) / SCAN_CHUNK;

  k_zero_i<<<512, 256, 0, stream>>>(deg, N);
  k_deg<<<EB, 256, 0, stream>>>(ei, deg, E);
  k_scan_part<<<NB, 256, 0, stream>>>(deg, part, N);
  k_scan_top<<<1, 256, 0, stream>>>(part, NB);
  k_scan_final<<<NB, 256, 0, stream>>>(deg, part, off, cursor, N, E);
  k_scatter<<<EB, 256, 0, stream>>>(ei, cursor, csr, E);

  k_gemm1<<<(N + 63) / 64, 256, 0, stream>>>(x, W1, attS1, attD1, h1, as1, ad1, N);
  k_fused1<<<(N + 3) / 4, 256, 0, stream>>>(csr, off, as1, ad1, h1, b1, h1b, N);

  k_gemm2<<<(N + 15) / 16, 256, 0, stream>>>(h1b, W2, h2, N);
  k_attn2<<<(N + 255) / 256, 256, 0, stream>>>(h2, attS2, attD2, as2, ad2, N);
  k_fused2<<<(N + 3) / 4, 256, 0, stream>>>(csr, off, as2, ad2, h2, b2, out, N);
}

// Round 6
// 353.124 us; speedup vs baseline: 5.4434x; 1.3332x over previous
//
#include <hip/hip_runtime.h>

// GAT 2-layer forward: CSR (rank-capture build), LDS-alpha fused aggregation.
// N=100000, E=1.6M, F_in=256, L1: 8 heads x 8 = 64, L2: 1 head x 16.

#define LRELU(v) ((v) > 0.f ? (v) : 0.2f * (v))
#define NEG_BIG -3.4e38f
#define SCAN_CHUNK 1024

__global__ __launch_bounds__(256) void k_zero_i(int* __restrict__ p, int n) {
  int i = blockIdx.x * 256 + threadIdx.x;
  int stride = gridDim.x * 256;
  for (; i < n; i += stride) p[i] = 0;
}

// rank[e] = position of edge e within its dst segment (atomicAdd return)
__global__ __launch_bounds__(256) void k_deg(const int* __restrict__ ei, int* __restrict__ deg,
                                             int* __restrict__ rank, int E) {
  int e = blockIdx.x * 256 + threadIdx.x;
  if (e >= E) return;
  rank[e] = atomicAdd(&deg[ei[E + e]], 1);
}

__global__ __launch_bounds__(256) void k_scan_part(const int* __restrict__ deg,
                                                   int* __restrict__ part, int N) {
  __shared__ int sm[256];
  const int t = threadIdx.x;
  const int base = blockIdx.x * SCAN_CHUNK + t * 4;
  int s = 0;
#pragma unroll
  for (int q = 0; q < 4; ++q) {
    int i = base + q;
    if (i < N) s += deg[i];
  }
  sm[t] = s;
  __syncthreads();
  for (int ofs = 128; ofs >= 1; ofs >>= 1) {
    if (t < ofs) sm[t] += sm[t + ofs];
    __syncthreads();
  }
  if (t == 0) part[blockIdx.x] = sm[0];
}

__global__ __launch_bounds__(256) void k_scan_top(int* __restrict__ part, int nb) {
  __shared__ int sm[256];
  const int t = threadIdx.x;
  sm[t] = (t < nb) ? part[t] : 0;
  __syncthreads();
  for (int ofs = 1; ofs < 256; ofs <<= 1) {
    int v = (t >= ofs) ? sm[t - ofs] : 0;
    __syncthreads();
    sm[t] += v;
    __syncthreads();
  }
  if (t < nb) part[t] = (t > 0) ? sm[t - 1] : 0;
}

__global__ __launch_bounds__(256) void k_scan_final(const int* __restrict__ deg,
                                                    const int* __restrict__ part,
                                                    int* __restrict__ off, int N, int E) {
  __shared__ int sm[256];
  const int t = threadIdx.x;
  const int base = blockIdx.x * SCAN_CHUNK + t * 4;
  int d[4];
  int s = 0;
#pragma unroll
  for (int q = 0; q < 4; ++q) {
    int i = base + q;
    d[q] = (i < N) ? deg[i] : 0;
    s += d[q];
  }
  sm[t] = s;
  __syncthreads();
  for (int ofs = 1; ofs < 256; ofs <<= 1) {
    int v = (t >= ofs) ? sm[t - ofs] : 0;
    __syncthreads();
    sm[t] += v;
    __syncthreads();
  }
  int run = part[blockIdx.x] + ((t > 0) ? sm[t - 1] : 0);
#pragma unroll
  for (int q = 0; q < 4; ++q) {
    int i = base + q;
    if (i < N) {
      off[i] = run;
      run += d[q];
    }
  }
  if (blockIdx.x == 0 && t == 0) off[N] = E;
}

// atomic-free scatter using precomputed rank
__global__ __launch_bounds__(256) void k_scatter(const int* __restrict__ ei,
                                                 const int* __restrict__ off,
                                                 const int* __restrict__ rank,
                                                 int* __restrict__ csr, int E) {
  int e = blockIdx.x * 256 + threadIdx.x;
  if (e >= E) return;
  csr[off[ei[E + e]] + rank[e]] = ei[e];
}

// h1[N,64] = x[N,256] @ W1[256,64], fused a_s/a_d epilogue.
__global__ __launch_bounds__(256) void k_gemm1(const float* __restrict__ x,
                                               const float* __restrict__ W,
                                               const float* __restrict__ attS,
                                               const float* __restrict__ attD,
                                               float* __restrict__ h1,
                                               float* __restrict__ a_s,
                                               float* __restrict__ a_d, int N) {
  __shared__ float sA[64][68];
  __shared__ float sW[64][64];
  const int t = threadIdx.x;
  const int n0 = blockIdx.x * 64;
  const int tr = t >> 4, tc = t & 15;
  const int tr4 = tr * 4, tc4 = tc * 4;

  float acc[4][4];
#pragma unroll
  for (int i = 0; i < 4; ++i)
#pragma unroll
    for (int j = 0; j < 4; ++j) acc[i][j] = 0.f;

  for (int c0 = 0; c0 < 256; c0 += 64) {
    {
      const int r = t >> 2, kq = (t & 3) * 16;
      const int n = n0 + r;
      float4 v[4];
      if (n < N) {
        const float4* xp = (const float4*)&x[(long)n * 256 + c0 + kq];
#pragma unroll
        for (int q = 0; q < 4; ++q) v[q] = xp[q];
      } else {
#pragma unroll
        for (int q = 0; q < 4; ++q) v[q] = make_float4(0.f, 0.f, 0.f, 0.f);
      }
#pragma unroll
      for (int q = 0; q < 4; ++q) {
        sA[kq + q * 4 + 0][r] = v[q].x;
        sA[kq + q * 4 + 1][r] = v[q].y;
        sA[kq + q * 4 + 2][r] = v[q].z;
        sA[kq + q * 4 + 3][r] = v[q].w;
      }
    }
#pragma unroll
    for (int i = 0; i < 4; ++i) {
      int idx = t + i * 256;
      int k = idx >> 4, col4 = (idx & 15) * 4;
      *(float4*)&sW[k][col4] = *(const float4*)&W[(long)(c0 + k) * 64 + col4];
    }
    __syncthreads();
#pragma unroll 16
    for (int k = 0; k < 64; ++k) {
      const float4 a = *(const float4*)&sA[k][tr4];
      const float4 b = *(const float4*)&sW[k][tc4];
      acc[0][0] += a.x * b.x; acc[0][1] += a.x * b.y; acc[0][2] += a.x * b.z; acc[0][3] += a.x * b.w;
      acc[1][0] += a.y * b.x; acc[1][1] += a.y * b.y; acc[1][2] += a.y * b.z; acc[1][3] += a.y * b.w;
      acc[2][0] += a.z * b.x; acc[2][1] += a.z * b.y; acc[2][2] += a.z * b.z; acc[2][3] += a.z * b.w;
      acc[3][0] += a.w * b.x; acc[3][1] += a.w * b.y; acc[3][2] += a.w * b.z; acc[3][3] += a.w * b.w;
    }
    __syncthreads();
  }

  const int head = tc >> 1;
  float attSv[4], attDv[4];
#pragma unroll
  for (int j = 0; j < 4; ++j) {
    int c7 = (tc4 + j) & 7;
    attSv[j] = attS[head * 8 + c7];
    attDv[j] = attD[head * 8 + c7];
  }
#pragma unroll
  for (int i = 0; i < 4; ++i) {
    const int n = n0 + tr4 + i;
    float ps = acc[i][0] * attSv[0] + acc[i][1] * attSv[1] + acc[i][2] * attSv[2] +
               acc[i][3] * attSv[3];
    float pd = acc[i][0] * attDv[0] + acc[i][1] * attDv[1] + acc[i][2] * attDv[2] +
               acc[i][3] * attDv[3];
    ps += __shfl_xor(ps, 1);
    pd += __shfl_xor(pd, 1);
    if (n < N) {
      *(float4*)&h1[(long)n * 64 + tc4] =
          make_float4(acc[i][0], acc[i][1], acc[i][2], acc[i][3]);
      if ((tc & 1) == 0) {
        a_s[n * 8 + head] = ps;
        a_d[n * 8 + head] = pd;
      }
    }
  }
}

// one wave per dst: softmax with per-edge-lane alpha -> LDS tile -> fma aggregation
__global__ __launch_bounds__(256) void k_fused1(const int* __restrict__ csr,
                                                const int* __restrict__ off,
                                                const float* __restrict__ as_,
                                                const float* __restrict__ ad_,
                                                const float* __restrict__ h1,
                                                const float* __restrict__ b1,
                                                float* __restrict__ h1b, int N) {
  __shared__ float aT[4][520];  // [wave][h*65 + edge]
  __shared__ int sT[4][64];
  const int wid = threadIdx.x >> 6;
  float* alds = aT[wid];
  int* slds = sT[wid];

  int wave = (blockIdx.x * 256 + threadIdx.x) >> 6;
  if (wave >= N) return;
  const int lane = threadIdx.x & 63;
  const int d = wave;
  const int r0 = off[d];
  const int deg = off[d + 1] - r0;

  if (deg == 0) {
    float v = b1[lane];
    h1b[(long)d * 64 + lane] = v > 0.f ? v : __expf(v) - 1.f;
    return;
  }

  const float4* dp = (const float4*)&ad_[(long)d * 8];
  float4 da = dp[0], db = dp[1];

  // pass 1: per-lane (one edge per lane) max over chunks; keep chunk0 e and src
  float em[8], e0[8];
  int s0 = 0;
#pragma unroll
  for (int h = 0; h < 8; ++h) em[h] = NEG_BIG;
  for (int j0 = 0; j0 < deg; j0 += 64) {
    int j = j0 + lane;
    float e[8];
    int s = 0;
    if (j < deg) {
      s = csr[r0 + j];
      const float4* ap = (const float4*)&as_[(long)s * 8];
      float4 a = ap[0], b = ap[1];
      e[0] = LRELU(a.x + da.x); e[1] = LRELU(a.y + da.y);
      e[2] = LRELU(a.z + da.z); e[3] = LRELU(a.w + da.w);
      e[4] = LRELU(b.x + db.x); e[5] = LRELU(b.y + db.y);
      e[6] = LRELU(b.z + db.z); e[7] = LRELU(b.w + db.w);
    } else {
#pragma unroll
      for (int h = 0; h < 8; ++h) e[h] = NEG_BIG;
    }
    if (j0 == 0) {
#pragma unroll
      for (int h = 0; h < 8; ++h) e0[h] = e[h];
      s0 = s;
    }
#pragma unroll
    for (int h = 0; h < 8; ++h) em[h] = fmaxf(em[h], e[h]);
  }
#pragma unroll
  for (int h = 0; h < 8; ++h) {
#pragma unroll
    for (int ofs = 32; ofs >= 1; ofs >>= 1) em[h] = fmaxf(em[h], __shfl_xor(em[h], ofs));
  }

  // pass 2: p0 (chunk0 exp) kept in regs; extra chunks recompute; reduce sum
  float p0[8], sm[8];
#pragma unroll
  for (int h = 0; h < 8; ++h) {
    p0[h] = __expf(e0[h] - em[h]);  // invalid lanes -> 0
    sm[h] = p0[h];
  }
  for (int j0 = 64; j0 < deg; j0 += 64) {
    int j = j0 + lane;
    if (j < deg) {
      int s = csr[r0 + j];
      const float4* ap = (const float4*)&as_[(long)s * 8];
      float4 a = ap[0], b = ap[1];
      float e[8];
      e[0] = LRELU(a.x + da.x); e[1] = LRELU(a.y + da.y);
      e[2] = LRELU(a.z + da.z); e[3] = LRELU(a.w + da.w);
      e[4] = LRELU(b.x + db.x); e[5] = LRELU(b.y + db.y);
      e[6] = LRELU(b.z + db.z); e[7] = LRELU(b.w + db.w);
#pragma unroll
      for (int h = 0; h < 8; ++h) sm[h] += __expf(e[h] - em[h]);
    }
  }
#pragma unroll
  for (int h = 0; h < 8; ++h) {
#pragma unroll
    for (int ofs = 32; ofs >= 1; ofs >>= 1) sm[h] += __shfl_xor(sm[h], ofs);
  }
  float inv[8];
#pragma unroll
  for (int h = 0; h < 8; ++h) inv[h] = 1.f / (sm[h] + 1e-16f);

  // pass 3: per chunk: store alpha tile + src tile, then fma aggregation
  const int hme = lane >> 3;
  const int hb = hme * 65;
  float acc = 0.f;
  for (int j0 = 0; j0 < deg; j0 += 64) {
    float p[8];
    int s;
    if (j0 == 0) {
#pragma unroll
      for (int h = 0; h < 8; ++h) p[h] = p0[h];
      s = s0;
    } else {
      int j = j0 + lane;
      s = 0;
      if (j < deg) {
        s = csr[r0 + j];
        const float4* ap = (const float4*)&as_[(long)s * 8];
        float4 a = ap[0], b = ap[1];
        float e[8];
        e[0] = LRELU(a.x + da.x); e[1] = LRELU(a.y + da.y);
        e[2] = LRELU(a.z + da.z); e[3] = LRELU(a.w + da.w);
        e[4] = LRELU(b.x + db.x); e[5] = LRELU(b.y + db.y);
        e[6] = LRELU(b.z + db.z); e[7] = LRELU(b.w + db.w);
#pragma unroll
        for (int h = 0; h < 8; ++h) p[h] = __expf(e[h] - em[h]);
      } else {
#pragma unroll
        for (int h = 0; h < 8; ++h) p[h] = 0.f;
      }
    }
#pragma unroll
    for (int h = 0; h < 8; ++h) alds[h * 65 + lane] = p[h] * inv[h];
    slds[lane] = s;
    __threadfence_block();

    const int cnt = min(64, deg - j0);
    int jj = 0;
    for (; jj + 4 <= cnt; jj += 4) {
      int t0 = slds[jj], t1 = slds[jj + 1], t2 = slds[jj + 2], t3 = slds[jj + 3];
      float a0 = alds[hb + jj], a1 = alds[hb + jj + 1];
      float a2 = alds[hb + jj + 2], a3 = alds[hb + jj + 3];
      float f0 = h1[(long)t0 * 64 + lane];
      float f1 = h1[(long)t1 * 64 + lane];
      float f2 = h1[(long)t2 * 64 + lane];
      float f3 = h1[(long)t3 * 64 + lane];
      acc += a0 * f0;
      acc += a1 * f1;
      acc += a2 * f2;
      acc += a3 * f3;
    }
    for (; jj < cnt; ++jj) acc += alds[hb + jj] * h1[(long)slds[jj] * 64 + lane];
    __threadfence_block();
  }
  float v = acc + b1[lane];
  h1b[(long)d * 64 + lane] = v > 0.f ? v : __expf(v) - 1.f;
}

// h2[N,16] = h1b[N,64] @ W2[64,16]
__global__ __launch_bounds__(256) void k_gemm2(const float* __restrict__ h1b,
                                               const float* __restrict__ W2,
                                               float* __restrict__ h2, int N) {
  __shared__ float sW[64][16];
  __shared__ float sX[16][64];
  const int t = threadIdx.x;
  const int n0 = blockIdx.x * 16;
  for (int i = t; i < 64 * 16; i += 256) sW[i >> 4][i & 15] = W2[i];
  for (int i = t; i < 16 * 64; i += 256) {
    int r = i >> 6, c = i & 63;
    int n = n0 + r;
    sX[r][c] = (n < N) ? h1b[(long)n * 64 + c] : 0.f;
  }
  __syncthreads();
  int c = t & 15, r = t >> 4;
  float acc = 0.f;
#pragma unroll
  for (int k = 0; k < 64; ++k) acc += sX[r][k] * sW[k][c];
  int n = n0 + r;
  if (n < N) h2[(long)n * 16 + c] = acc;
}

__global__ __launch_bounds__(256) void k_attn2(const float* __restrict__ h2,
                                               const float* __restrict__ attS,
                                               const float* __restrict__ attD,
                                               float* __restrict__ a_s,
                                               float* __restrict__ a_d, int N) {
  int n = blockIdx.x * 256 + threadIdx.x;
  if (n >= N) return;
  const float4* hp = (const float4*)&h2[(long)n * 16];
  float ss = 0.f, dd = 0.f;
#pragma unroll
  for (int q = 0; q < 4; ++q) {
    float4 v = hp[q];
    float4 sv = ((const float4*)attS)[q];
    float4 dv = ((const float4*)attD)[q];
    ss += v.x * sv.x + v.y * sv.y + v.z * sv.z + v.w * sv.w;
    dd += v.x * dv.x + v.y * dv.y + v.z * dv.z + v.w * dv.w;
  }
  a_s[n] = ss;
  a_d[n] = dd;
}

// one wave per dst: LDS-alpha softmax + quarter-wave aggregation + bias + log_softmax
__global__ __launch_bounds__(256) void k_fused2(const int* __restrict__ csr,
                                                const int* __restrict__ off,
                                                const float* __restrict__ as_,
                                                const float* __restrict__ ad_,
                                                const float* __restrict__ h2,
                                                const float* __restrict__ b2,
                                                float* __restrict__ out, int N) {
  __shared__ float aT[4][64];
  __shared__ int sT[4][64];
  const int wid = threadIdx.x >> 6;
  float* alds = aT[wid];
  int* slds = sT[wid];

  int wave = (blockIdx.x * 256 + threadIdx.x) >> 6;
  if (wave >= N) return;
  const int lane = threadIdx.x & 63;
  const int d = wave;
  const int r0 = off[d];
  const int deg = off[d + 1] - r0;
  const float add = ad_[d];

  float em = NEG_BIG, e0 = NEG_BIG;
  int s0 = 0;
  for (int j0 = 0; j0 < deg; j0 += 64) {
    int j = j0 + lane;
    float e = NEG_BIG;
    int s = 0;
    if (j < deg) {
      s = csr[r0 + j];
      e = LRELU(as_[s] + add);
    }
    if (j0 == 0) { e0 = e; s0 = s; }
    em = fmaxf(em, e);
  }
#pragma unroll
  for (int ofs = 32; ofs >= 1; ofs >>= 1) em = fmaxf(em, __shfl_xor(em, ofs));

  float p0 = (deg > 0) ? __expf(e0 - em) : 0.f;
  float sm = p0;
  for (int j0 = 64; j0 < deg; j0 += 64) {
    int j = j0 + lane;
    if (j < deg) sm += __expf(LRELU(as_[csr[r0 + j]] + add) - em);
  }
#pragma unroll
  for (int ofs = 32; ofs >= 1; ofs >>= 1) sm += __shfl_xor(sm, ofs);
  const float inv = 1.f / (sm + 1e-16f);

  const int sub = lane >> 4, col = lane & 15;
  float acc = 0.f;
  for (int j0 = 0; j0 < deg; j0 += 64) {
    float p;
    int s;
    if (j0 == 0) {
      p = p0;
      s = s0;
    } else {
      int j = j0 + lane;
      p = 0.f;
      s = 0;
      if (j < deg) {
        s = csr[r0 + j];
        p = __expf(LRELU(as_[s] + add) - em);
      }
    }
    alds[lane] = p * inv;
    slds[lane] = s;
    __threadfence_block();

    const int cnt = min(64, deg - j0);
    int j = sub;
    for (; j + 4 < cnt; j += 8) {
      int t0 = slds[j], t1 = slds[j + 4];
      float a0 = alds[j], a1 = alds[j + 4];
      float f0 = h2[(long)t0 * 16 + col], f1 = h2[(long)t1 * 16 + col];
      acc += a0 * f0 + a1 * f1;
    }
    for (; j < cnt; j += 4) acc += alds[j] * h2[(long)slds[j] * 16 + col];
    __threadfence_block();
  }
  acc += __shfl_xor(acc, 16);
  acc += __shfl_xor(acc, 32);

  float v = acc + b2[col];
  float mm = v;
#pragma unroll
  for (int ofs = 1; ofs < 16; ofs <<= 1) mm = fmaxf(mm, __shfl_xor(mm, ofs));
  float ex = __expf(v - mm), ssum = ex;
#pragma unroll
  for (int ofs = 1; ofs < 16; ofs <<= 1) ssum += __shfl_xor(ssum, ofs);
  if (sub == 0) out[(long)d * 16 + col] = v - (mm + __logf(ssum));
}

extern "C" void kernel_launch(void* const* d_in, const int* in_sizes, int n_in,
                              void* d_out, int out_size, void* d_ws, size_t ws_size,
                              hipStream_t stream) {
  const float* x = (const float*)d_in[0];
  const int* ei = (const int*)d_in[1];
  const float* W1 = (const float*)d_in[2];
  const float* attS1 = (const float*)d_in[3];
  const float* attD1 = (const float*)d_in[4];
  const float* b1 = (const float*)d_in[5];
  const float* W2 = (const float*)d_in[6];
  const float* attS2 = (const float*)d_in[7];
  const float* attD2 = (const float*)d_in[8];
  const float* b2 = (const float*)d_in[9];
  float* out = (float*)d_out;

  const int N = in_sizes[0] / 256;
  const int E = in_sizes[1] / 2;

  // ws layout (float offsets):
  // [0,64N): h1 (layer2: h2 at 0, as2 at 16N, ad2 at 17N)
  // [64N,128N): h1b; rank (E=16N ints) overlays [64N,80N) before fused1
  // [128N,144N): csr   [144N,146N): off   [146N,147N): deg   [148N,149N): part
  float* ws = (float*)d_ws;
  float* h1 = ws;
  float* h1b = ws + (long)64 * N;
  int* rank = (int*)(ws + (long)64 * N);
  int* csr = (int*)(ws + (long)128 * N);
  int* off = (int*)(ws + (long)144 * N);
  int* deg = (int*)(ws + (long)146 * N);
  int* part = (int*)(ws + (long)148 * N);

  float* h2 = ws;
  float* as2 = ws + (long)16 * N;
  float* ad2 = ws + (long)17 * N;

  float* as1 = out;
  float* ad1 = out + (long)8 * N;

  const int EB = (E + 255) / 256;
  const int NB = (N + SCAN_CHUNK - 1) / SCAN_CHUNK;

  k_zero_i<<<512, 256, 0, stream>>>(deg, N);
  k_deg<<<EB, 256, 0, stream>>>(ei, deg, rank, E);
  k_scan_part<<<NB, 256, 0, stream>>>(deg, part, N);
  k_scan_top<<<1, 256, 0, stream>>>(part, NB);
  k_scan_final<<<NB, 256, 0, stream>>>(deg, part, off, N, E);
  k_scatter<<<EB, 256, 0, stream>>>(ei, off, rank, csr, E);

  k_gemm1<<<(N + 63) / 64, 256, 0, stream>>>(x, W1, attS1, attD1, h1, as1, ad1, N);
  k_fused1<<<(N + 3) / 4, 256, 0, stream>>>(csr, off, as1, ad1, h1, b1, h1b, N);

  k_gemm2<<<(N + 15) / 16, 256, 0, stream>>>(h1b, W2, h2, N);
  k_attn2<<<(N + 255) / 256, 256, 0, stream>>>(h2, attS2, attD2, as2, ad2, N);
  k_fused2<<<(N + 3) / 4, 256, 0, stream>>>(csr, off, as2, ad2, h2, b2, out, N);
}